// Round 2
// baseline (497.794 us; speedup 1.0000x reference)
//
#include <hip/hip_runtime.h>
#include <cstdint>
#include <cstddef>

// SlotAttention fused fp32, round 1.
// Key refactor: k/v are never materialized.
//   dots  = (q @ Wk) . x_ln  + q.bk      (qk is [32,8,256], tiny)
//   updates = Wv @ (sum_j x_ln * attn_eps)/S + bv   (1/S factors out of sum)
// Workspace need: ~1.84 MB (round-0's 274 MB demand is the suspected crash).

#define NTOK 4096
#define DDIM 256
#define NSLOT 8
#define NBATCH 32
#define NROWS (NBATCH * NTOK)   // 131072 token rows
#define SROWS (NBATCH * NSLOT)  // 256 slot rows
#define SCALE 0.0625f           // d^-0.5
#define LN_EPS_C 1e-5f
#define ATTN_EPS_C 1e-8f

__device__ __forceinline__ void wave_reduce2(float& s, float& ss) {
#pragma unroll
  for (int off = 32; off > 0; off >>= 1) {
    s  += __shfl_down(s, off, 64);
    ss += __shfl_down(ss, off, 64);
  }
}

// slots = mu + exp(logsigma) * noise
__global__ __launch_bounds__(256) void init_slots_k(
    const float* __restrict__ noise, const float* __restrict__ mu,
    const float* __restrict__ logsig, float* __restrict__ slots) {
  int i = blockIdx.x * 256 + threadIdx.x;
  int d = i & (DDIM - 1);
  slots[i] = mu[d] + expf(logsig[d]) * noise[i];
}

// per-token-row mean / rstd of inputs (LN recomputed inline downstream)
__global__ __launch_bounds__(256) void row_stats_k(
    const float* __restrict__ X, float* __restrict__ mean,
    float* __restrict__ rstd) {
  int row = blockIdx.x * 4 + (threadIdx.x >> 6);
  int lane = threadIdx.x & 63;
  const float* xr = X + (size_t)row * DDIM;
  float4 a = *(const float4*)(xr + lane * 4);
  float s = a.x + a.y + a.z + a.w;
  float ss = a.x * a.x + a.y * a.y + a.z * a.z + a.w * a.w;
  wave_reduce2(s, ss);
  if (lane == 0) {
    float m = s * (1.f / DDIM);
    float v = ss * (1.f / DDIM) - m * m;
    mean[row] = m;
    rstd[row] = rsqrtf(v + LN_EPS_C);
  }
}

// per slot row r: LN(slots) -> q -> qk = SCALE*(q @ Wk), qkb = SCALE*(q.bk)
// also zeroes u_unnorm and S for this iteration (stream-ordered before atomics)
__global__ __launch_bounds__(256) void q_qk_k(
    const float* __restrict__ slots, const float* __restrict__ g_sl,
    const float* __restrict__ be_sl, const float* __restrict__ Wq,
    const float* __restrict__ bq, const float* __restrict__ Wk,
    const float* __restrict__ bk, float* __restrict__ qk,
    float* __restrict__ qkb, float* __restrict__ u_unnorm,
    float* __restrict__ S) {
  __shared__ float ln[DDIM], sq[DDIM];
  __shared__ float red[8];
  int r = blockIdx.x, t = threadIdx.x;
  u_unnorm[r * DDIM + t] = 0.f;
  if (t == 0) S[r] = 0.f;
  float val = slots[(size_t)r * DDIM + t];
  float s = val, ss = val * val;
  wave_reduce2(s, ss);
  int lane = t & 63, wid = t >> 6;
  if (lane == 0) { red[wid] = s; red[4 + wid] = ss; }
  __syncthreads();
  s = red[0] + red[1] + red[2] + red[3];
  ss = red[4] + red[5] + red[6] + red[7];
  float m = s * (1.f / DDIM);
  float var = ss * (1.f / DDIM) - m * m;
  float rs = rsqrtf(var + LN_EPS_C);
  ln[t] = (val - m) * rs * g_sl[t] + be_sl[t];
  __syncthreads();
  // q[t] = bq[t] + ln . Wq[t,:]
  float acc = bq[t];
  const float* wr = Wq + (size_t)t * DDIM;
  for (int d = 0; d < DDIM; d += 4) {
    float4 w4 = *(const float4*)(wr + d);
    float4 l4 = *(const float4*)&ln[d];
    acc += l4.x * w4.x + l4.y * w4.y + l4.z * w4.z + l4.w * w4.w;
  }
  sq[t] = acc;
  __syncthreads();
  // qk[r,t] = SCALE * sum_o sq[o] * Wk[o,t]  (coalesced over t)
  float a2 = 0.f;
  for (int o = 0; o < DDIM; o += 4) {
    a2 += sq[o]     * Wk[(size_t)o * DDIM + t]
        + sq[o + 1] * Wk[(size_t)(o + 1) * DDIM + t]
        + sq[o + 2] * Wk[(size_t)(o + 2) * DDIM + t]
        + sq[o + 3] * Wk[(size_t)(o + 3) * DDIM + t];
  }
  qk[(size_t)r * DDIM + t] = SCALE * a2;
  // qkb[r] = SCALE * sum_o sq[o]*bk[o]
  float pb = acc * bk[t], dummy = 0.f;
  wave_reduce2(pb, dummy);
  __syncthreads();
  if (lane == 0) red[wid] = pb;
  __syncthreads();
  if (t == 0) qkb[r] = SCALE * (red[0] + red[1] + red[2] + red[3]);
}

// thread = token: dots[i] = qk[i,:].x_ln + qkb[i]; softmax over 8 slots;
// write attn to d_out; accumulate S[b,i] += sum_j (attn+eps)
__global__ __launch_bounds__(256) void dots_k(
    const float* __restrict__ X, const float* __restrict__ mean,
    const float* __restrict__ rstd, const float* __restrict__ g,
    const float* __restrict__ be, const float* __restrict__ qk,
    const float* __restrict__ qkb, float* __restrict__ attn_out,
    float* __restrict__ S) {
  __shared__ float sqk[NSLOT][DDIM];
  __shared__ float sg[DDIM], sbe[DDIM];
  __shared__ float sqkb[NSLOT];
  __shared__ float partial[4][NSLOT];
  int b = blockIdx.x, t = threadIdx.x;
  int j = blockIdx.y * 256 + t;
#pragma unroll
  for (int p = 0; p < NSLOT; ++p)
    sqk[p][t] = qk[((size_t)b * NSLOT + p) * DDIM + t];
  sg[t] = g[t];
  sbe[t] = be[t];
  if (t < NSLOT) sqkb[t] = qkb[b * NSLOT + t];
  __syncthreads();
  int row = b * NTOK + j;
  const float* xr = X + (size_t)row * DDIM;
  float m = mean[row], rs = rstd[row];
  float dots[NSLOT];
#pragma unroll
  for (int i = 0; i < NSLOT; ++i) dots[i] = sqkb[i];
  for (int d = 0; d < DDIM; d += 4) {
    float4 xv = *(const float4*)(xr + d);
    float4 gv = *(const float4*)&sg[d];
    float4 bev = *(const float4*)&sbe[d];
    float l0 = (xv.x - m) * rs * gv.x + bev.x;
    float l1 = (xv.y - m) * rs * gv.y + bev.y;
    float l2 = (xv.z - m) * rs * gv.z + bev.z;
    float l3 = (xv.w - m) * rs * gv.w + bev.w;
#pragma unroll
    for (int i = 0; i < NSLOT; ++i) {
      dots[i] += l0 * sqk[i][d] + l1 * sqk[i][d + 1] + l2 * sqk[i][d + 2] +
                 l3 * sqk[i][d + 3];
    }
  }
  float mx = -1e30f;
#pragma unroll
  for (int i = 0; i < NSLOT; ++i) mx = fmaxf(mx, dots[i]);
  float sum = 0.f;
#pragma unroll
  for (int i = 0; i < NSLOT; ++i) { dots[i] = expf(dots[i] - mx); sum += dots[i]; }
  float inv = 1.f / sum;
  int lane = t & 63, wid = t >> 6;
#pragma unroll
  for (int i = 0; i < NSLOT; ++i) {
    float a = dots[i] * inv;
    attn_out[((size_t)b * NSLOT + i) * NTOK + j] = a;
    float ps = a + ATTN_EPS_C;
#pragma unroll
    for (int off = 32; off > 0; off >>= 1) ps += __shfl_down(ps, off, 64);
    if (lane == 0) partial[wid][i] = ps;
  }
  __syncthreads();
  if (t < NSLOT) {
    float s4 = partial[0][t] + partial[1][t] + partial[2][t] + partial[3][t];
    atomicAdd(&S[b * NSLOT + t], s4);
  }
}

// thread = dim d: u_unnorm[b,i,d] += sum_{j in chunk} x_ln[j,d]*(attn[i,j]+eps)
// fully coalesced x reads
__global__ __launch_bounds__(256) void updates_pass_k(
    const float* __restrict__ X, const float* __restrict__ mean,
    const float* __restrict__ rstd, const float* __restrict__ g,
    const float* __restrict__ be, const float* __restrict__ attn,
    float* __restrict__ u_unnorm) {
  __shared__ float sa[NSLOT][256];
  int b = blockIdx.x, t = threadIdx.x;
  int j0 = blockIdx.y * 256;
#pragma unroll
  for (int p = 0; p < NSLOT; ++p)
    sa[p][t] = attn[((size_t)b * NSLOT + p) * NTOK + j0 + t] + ATTN_EPS_C;
  __syncthreads();
  float gt = g[t], bet = be[t];
  float acc[NSLOT] = {};
  const float* xb = X + ((size_t)(b * NTOK + j0)) * DDIM + t;
  const float* mb = mean + b * NTOK + j0;
  const float* rb = rstd + b * NTOK + j0;
  for (int jj = 0; jj < 256; ++jj) {
    float xv = xb[(size_t)jj * DDIM];
    float xl = (xv - mb[jj]) * rb[jj] * gt + bet;
#pragma unroll
    for (int i = 0; i < NSLOT; ++i) acc[i] = fmaf(xl, sa[i][jj], acc[i]);
  }
#pragma unroll
  for (int i = 0; i < NSLOT; ++i)
    atomicAdd(&u_unnorm[((size_t)b * NSLOT + i) * DDIM + t], acc[i]);
}

// per slot row: updates = (u/S)@Wv^T + bv -> GRU -> slots' -> +MLP(LN(slots'))
__global__ __launch_bounds__(256) void upd_gru_ff_k(
    const float* __restrict__ u_unnorm, const float* __restrict__ S,
    const float* __restrict__ slots_in, const float* __restrict__ Wv,
    const float* __restrict__ bv, const float* __restrict__ W_ih,
    const float* __restrict__ W_hh, const float* __restrict__ b_ih,
    const float* __restrict__ b_hh, const float* __restrict__ g_ff,
    const float* __restrict__ be_ff, const float* __restrict__ W1,
    const float* __restrict__ b1, const float* __restrict__ W2,
    const float* __restrict__ b2, float* __restrict__ slots_out) {
  __shared__ float su[DDIM], sh[DDIM], supd[DDIM], pre[DDIM], hid[DDIM];
  __shared__ float red[8];
  int r = blockIdx.x, t = threadIdx.x;
  float invS = 1.f / S[r];
  su[t] = u_unnorm[(size_t)r * DDIM + t] * invS;
  float hval = slots_in[(size_t)r * DDIM + t];
  sh[t] = hval;
  __syncthreads();
  // updates[t] = bv[t] + su . Wv[t,:]
  float upd = bv[t];
  const float* wvr = Wv + (size_t)t * DDIM;
  for (int d = 0; d < DDIM; d += 4) {
    float4 w4 = *(const float4*)(wvr + d);
    float4 u4 = *(const float4*)&su[d];
    upd += u4.x * w4.x + u4.y * w4.y + u4.z * w4.z + u4.w * w4.w;
  }
  supd[t] = upd;
  __syncthreads();
  // GRU gates
  float air = b_ih[t], aiz = b_ih[DDIM + t], ain = b_ih[2 * DDIM + t];
  float ahr = b_hh[t], ahz = b_hh[DDIM + t], ahn = b_hh[2 * DDIM + t];
  const float* wir = W_ih + (size_t)t * DDIM;
  const float* wiz = W_ih + (size_t)(DDIM + t) * DDIM;
  const float* win = W_ih + (size_t)(2 * DDIM + t) * DDIM;
  const float* whr = W_hh + (size_t)t * DDIM;
  const float* whz = W_hh + (size_t)(DDIM + t) * DDIM;
  const float* whn = W_hh + (size_t)(2 * DDIM + t) * DDIM;
  for (int d = 0; d < DDIM; d += 4) {
    float4 u4 = *(const float4*)&supd[d];
    float4 h4 = *(const float4*)&sh[d];
    float4 w;
    w = *(const float4*)(wir + d);
    air += u4.x * w.x + u4.y * w.y + u4.z * w.z + u4.w * w.w;
    w = *(const float4*)(wiz + d);
    aiz += u4.x * w.x + u4.y * w.y + u4.z * w.z + u4.w * w.w;
    w = *(const float4*)(win + d);
    ain += u4.x * w.x + u4.y * w.y + u4.z * w.z + u4.w * w.w;
    w = *(const float4*)(whr + d);
    ahr += h4.x * w.x + h4.y * w.y + h4.z * w.z + h4.w * w.w;
    w = *(const float4*)(whz + d);
    ahz += h4.x * w.x + h4.y * w.y + h4.z * w.z + h4.w * w.w;
    w = *(const float4*)(whn + d);
    ahn += h4.x * w.x + h4.y * w.y + h4.z * w.z + h4.w * w.w;
  }
  float rg = 1.f / (1.f + expf(-(air + ahr)));
  float zg = 1.f / (1.f + expf(-(aiz + ahz)));
  float ng = tanhf(ain + rg * ahn);
  float nh = (1.f - zg) * ng + zg * hval;
  // FF: LN stats on new slots row
  float s2 = nh, ss2 = nh * nh;
  wave_reduce2(s2, ss2);
  int lane = t & 63, wid = t >> 6;
  if (lane == 0) { red[wid] = s2; red[4 + wid] = ss2; }
  __syncthreads();
  s2 = red[0] + red[1] + red[2] + red[3];
  ss2 = red[4] + red[5] + red[6] + red[7];
  float m2 = s2 * (1.f / DDIM);
  float v2 = ss2 * (1.f / DDIM) - m2 * m2;
  float rs2 = rsqrtf(v2 + LN_EPS_C);
  pre[t] = (nh - m2) * rs2 * g_ff[t] + be_ff[t];
  __syncthreads();
  float ac1 = b1[t];
  const float* w1r = W1 + (size_t)t * DDIM;
  for (int d = 0; d < DDIM; d += 4) {
    float4 w4 = *(const float4*)(w1r + d);
    float4 p4 = *(const float4*)&pre[d];
    ac1 += p4.x * w4.x + p4.y * w4.y + p4.z * w4.z + p4.w * w4.w;
  }
  hid[t] = fmaxf(ac1, 0.f);
  __syncthreads();
  float ac2 = b2[t];
  const float* w2r = W2 + (size_t)t * DDIM;
  for (int d = 0; d < DDIM; d += 4) {
    float4 w4 = *(const float4*)(w2r + d);
    float4 h4 = *(const float4*)&hid[d];
    ac2 += h4.x * w4.x + h4.y * w4.y + h4.z * w4.z + h4.w * w4.w;
  }
  slots_out[(size_t)r * DDIM + t] = nh + ac2;
}

extern "C" void kernel_launch(void* const* d_in, const int* in_sizes, int n_in,
                              void* d_out, int out_size, void* d_ws,
                              size_t ws_size, hipStream_t stream) {
  const float* inputs   = (const float*)d_in[0];
  const float* noise    = (const float*)d_in[1];
  const float* slots_mu = (const float*)d_in[2];
  const float* slots_ls = (const float*)d_in[3];
  const float* Wq   = (const float*)d_in[4];
  const float* bq   = (const float*)d_in[5];
  const float* Wk   = (const float*)d_in[6];
  const float* bk   = (const float*)d_in[7];
  const float* Wv   = (const float*)d_in[8];
  const float* bv   = (const float*)d_in[9];
  const float* W_ih = (const float*)d_in[10];
  const float* W_hh = (const float*)d_in[11];
  const float* b_ih = (const float*)d_in[12];
  const float* b_hh = (const float*)d_in[13];
  const float* W1   = (const float*)d_in[14];
  const float* b1   = (const float*)d_in[15];
  const float* W2   = (const float*)d_in[16];
  const float* b2   = (const float*)d_in[17];
  const float* g_in = (const float*)d_in[18];
  const float* be_in= (const float*)d_in[19];
  const float* g_sl = (const float*)d_in[20];
  const float* be_sl= (const float*)d_in[21];
  const float* g_ff = (const float*)d_in[22];
  const float* be_ff= (const float*)d_in[23];

  float* out_slots = (float*)d_out;                 // [32,8,256]
  float* out_attn  = (float*)d_out + SROWS * DDIM;  // [32,8,4096]

  float* w = (float*)d_ws;
  float* mean = w;     w += NROWS;        // 131072
  float* rstd = w;     w += NROWS;        // 131072
  float* slots = w;    w += SROWS * DDIM; // 65536
  float* qk = w;       w += SROWS * DDIM; // 65536
  float* qkb = w;      w += SROWS;        // 256
  float* S = w;        w += SROWS;        // 256
  float* u_unnorm = w; w += SROWS * DDIM; // 65536
  // total ~1.84 MB

  init_slots_k<<<SROWS, 256, 0, stream>>>(noise, slots_mu, slots_ls, slots);
  row_stats_k<<<NROWS / 4, 256, 0, stream>>>(inputs, mean, rstd);

  for (int it = 0; it < 3; ++it) {
    q_qk_k<<<SROWS, 256, 0, stream>>>(slots, g_sl, be_sl, Wq, bq, Wk, bk, qk,
                                      qkb, u_unnorm, S);
    dots_k<<<dim3(NBATCH, 16), 256, 0, stream>>>(inputs, mean, rstd, g_in,
                                                 be_in, qk, qkb, out_attn, S);
    updates_pass_k<<<dim3(NBATCH, 16), 256, 0, stream>>>(
        inputs, mean, rstd, g_in, be_in, out_attn, u_unnorm);
    float* sout = (it == 2) ? out_slots : slots;
    upd_gru_ff_k<<<SROWS, 256, 0, stream>>>(u_unnorm, S, slots, Wv, bv, W_ih,
                                            W_hh, b_ih, b_hh, g_ff, be_ff, W1,
                                            b1, W2, b2, sout);
  }
}

// Round 3
// 487.762 us; speedup vs baseline: 1.0206x; 1.0206x over previous
//
#include <hip/hip_runtime.h>
#include <cstdint>
#include <cstddef>

// SlotAttention fused fp32, round 2.
//  - k/v never materialized (dots via qk = SCALE*q@Wk; updates via Wv@(sum x_ln*attn)/S)
//  - weights pre-transposed once per call -> all slot-path matvecs coalesced
//  - dots+softmax+update-accumulation fused into ONE pass over X per iteration
//  - row LN stats computed inline (no separate row_stats pass)

#define NTOK 4096
#define DDIM 256
#define NSLOT 8
#define NBATCH 32
#define NROWS (NBATCH * NTOK)   // 131072 token rows
#define SROWS (NBATCH * NSLOT)  // 256 slot rows
#define SCALE 0.0625f           // d^-0.5
#define LN_EPS_C 1e-5f
#define ATTN_EPS_C 1e-8f

__device__ __forceinline__ void wave_reduce2(float& s, float& ss) {
#pragma unroll
  for (int off = 32; off > 0; off >>= 1) {
    s  += __shfl_down(s, off, 64);
    ss += __shfl_down(ss, off, 64);
  }
}

// slots = mu + exp(logsigma) * noise
__global__ __launch_bounds__(256) void init_slots_k(
    const float* __restrict__ noise, const float* __restrict__ mu,
    const float* __restrict__ logsig, float* __restrict__ slots) {
  int i = blockIdx.x * 256 + threadIdx.x;
  int d = i & (DDIM - 1);
  slots[i] = mu[d] + expf(logsig[d]) * noise[i];
}

// One launch transposing all six weight matrices.
// grid.x tiles: Wq[0,8) Wv[8,16) W_ih[16,40) W_hh[40,64) W1[64,72) W2[72,80)
// All inputs are [O, 256] row-major; outputs are [256, O].
__global__ __launch_bounds__(256) void transpose_all_k(
    const float* __restrict__ Wq, const float* __restrict__ Wv,
    const float* __restrict__ Wih, const float* __restrict__ Whh,
    const float* __restrict__ W1, const float* __restrict__ W2,
    float* __restrict__ WqT, float* __restrict__ WvT,
    float* __restrict__ WihT, float* __restrict__ WhhT,
    float* __restrict__ W1T, float* __restrict__ W2T) {
  __shared__ float tile[32][33];
  int bz = blockIdx.x;
  const float* in; float* out; int O, bo;
  if (bz < 8)       { in = Wq;  out = WqT;  O = 256; bo = bz; }
  else if (bz < 16) { in = Wv;  out = WvT;  O = 256; bo = bz - 8; }
  else if (bz < 40) { in = Wih; out = WihT; O = 768; bo = bz - 16; }
  else if (bz < 64) { in = Whh; out = WhhT; O = 768; bo = bz - 40; }
  else if (bz < 72) { in = W1;  out = W1T;  O = 256; bo = bz - 64; }
  else              { in = W2;  out = W2T;  O = 256; bo = bz - 72; }
  int tx = threadIdx.x & 31, ty = threadIdx.x >> 5;  // 32 x 8
  int ro = bo * 32, cd = blockIdx.y * 32;
#pragma unroll
  for (int p = 0; p < 32; p += 8)
    tile[ty + p][tx] = in[(size_t)(ro + ty + p) * DDIM + cd + tx];
  __syncthreads();
#pragma unroll
  for (int p = 0; p < 32; p += 8)
    out[(size_t)(cd + ty + p) * O + ro + tx] = tile[tx][ty + p];
}

// per slot row r: LN(slots) -> q (via WqT, coalesced) -> qk = SCALE*(q @ Wk),
// qkb = SCALE*(q.bk); zeroes u_unnorm and S for the coming iteration.
__global__ __launch_bounds__(256) void q_qk_k(
    const float* __restrict__ slots, const float* __restrict__ g_sl,
    const float* __restrict__ be_sl, const float* __restrict__ WqT,
    const float* __restrict__ bq, const float* __restrict__ Wk,
    const float* __restrict__ bk, float* __restrict__ qk,
    float* __restrict__ qkb, float* __restrict__ u_unnorm,
    float* __restrict__ S) {
  __shared__ float ln[DDIM], sq[DDIM];
  __shared__ float red[8];
  int r = blockIdx.x, t = threadIdx.x;
  u_unnorm[r * DDIM + t] = 0.f;
  if (t == 0) S[r] = 0.f;
  float val = slots[(size_t)r * DDIM + t];
  float s = val, ss = val * val;
  wave_reduce2(s, ss);
  int lane = t & 63, wid = t >> 6;
  if (lane == 0) { red[wid] = s; red[4 + wid] = ss; }
  __syncthreads();
  s = red[0] + red[1] + red[2] + red[3];
  ss = red[4] + red[5] + red[6] + red[7];
  float m = s * (1.f / DDIM);
  float var = ss * (1.f / DDIM) - m * m;
  float rs = rsqrtf(var + LN_EPS_C);
  ln[t] = (val - m) * rs * g_sl[t] + be_sl[t];
  __syncthreads();
  // q[t] = bq[t] + sum_d ln[d] * WqT[d][t]   (coalesced)
  float acc = bq[t];
  {
    const float* p = WqT + t;
#pragma unroll 8
    for (int d = 0; d < DDIM; ++d) acc = fmaf(ln[d], p[(size_t)d * DDIM], acc);
  }
  sq[t] = acc;
  __syncthreads();
  // qk[r,t] = SCALE * sum_o sq[o] * Wk[o][t]  (coalesced)
  float a2 = 0.f;
  {
    const float* p = Wk + t;
#pragma unroll 8
    for (int o = 0; o < DDIM; ++o) a2 = fmaf(sq[o], p[(size_t)o * DDIM], a2);
  }
  qk[(size_t)r * DDIM + t] = SCALE * a2;
  // qkb[r] = SCALE * sum_o sq[o]*bk[o]
  float pb = acc * bk[t], dummy = 0.f;
  wave_reduce2(pb, dummy);
  __syncthreads();
  if (lane == 0) red[wid] = pb;
  __syncthreads();
  if (t == 0) qkb[r] = SCALE * (red[0] + red[1] + red[2] + red[3]);
}

// ONE pass over X per iteration:
//  phase 0 (thread=token): row LN stats
//  phase 1 (thread=token): dots = qk . x_ln + qkb ; softmax over 8 slots ->
//          attn (LDS; global write only on last iter); partial S
//  phase 2 (thread=dim):   u_unnorm[b,i,:] += sum_j x_ln[j,:]*(attn[i,j]+eps)
__global__ __launch_bounds__(256) void fused_attn_k(
    const float* __restrict__ X, const float* __restrict__ g,
    const float* __restrict__ be, const float* __restrict__ qk,
    const float* __restrict__ qkb, float* __restrict__ attn_out,
    float* __restrict__ S, float* __restrict__ u_unnorm, int write_attn) {
  __shared__ float sqk[NSLOT][DDIM];
  __shared__ float sg[DDIM], sbe[DDIM];
  __shared__ float sm[256], srd[256];
  __shared__ float sa[NSLOT][256];
  __shared__ float sqkb[NSLOT];
  __shared__ float partial[4][NSLOT];
  int b = blockIdx.x, t = threadIdx.x;
  int j0 = blockIdx.y * 256;
  int j = j0 + t;
#pragma unroll
  for (int p = 0; p < NSLOT; ++p)
    sqk[p][t] = qk[((size_t)b * NSLOT + p) * DDIM + t];
  sg[t] = g[t];
  sbe[t] = be[t];
  if (t < NSLOT) sqkb[t] = qkb[b * NSLOT + t];
  const float* xr = X + ((size_t)b * NTOK + j) * DDIM;
  // phase 0: stats
  float s = 0.f, ss = 0.f;
  for (int d = 0; d < DDIM; d += 4) {
    float4 xv = *(const float4*)(xr + d);
    s += xv.x + xv.y + xv.z + xv.w;
    ss += xv.x * xv.x + xv.y * xv.y + xv.z * xv.z + xv.w * xv.w;
  }
  float m = s * (1.f / DDIM);
  float rs = rsqrtf(ss * (1.f / DDIM) - m * m + LN_EPS_C);
  sm[t] = m;
  srd[t] = rs;
  __syncthreads();
  // phase 1: dots + softmax
  float dots[NSLOT];
#pragma unroll
  for (int i = 0; i < NSLOT; ++i) dots[i] = sqkb[i];
  for (int d = 0; d < DDIM; d += 4) {
    float4 xv = *(const float4*)(xr + d);
    float4 gv = *(const float4*)&sg[d];
    float4 bev = *(const float4*)&sbe[d];
    float l0 = (xv.x - m) * rs * gv.x + bev.x;
    float l1 = (xv.y - m) * rs * gv.y + bev.y;
    float l2 = (xv.z - m) * rs * gv.z + bev.z;
    float l3 = (xv.w - m) * rs * gv.w + bev.w;
#pragma unroll
    for (int i = 0; i < NSLOT; ++i) {
      dots[i] += l0 * sqk[i][d] + l1 * sqk[i][d + 1] + l2 * sqk[i][d + 2] +
                 l3 * sqk[i][d + 3];
    }
  }
  float mx = -1e30f;
#pragma unroll
  for (int i = 0; i < NSLOT; ++i) mx = fmaxf(mx, dots[i]);
  float sum = 0.f;
#pragma unroll
  for (int i = 0; i < NSLOT; ++i) { dots[i] = expf(dots[i] - mx); sum += dots[i]; }
  float inv = 1.f / sum;
  int lane = t & 63, wid = t >> 6;
#pragma unroll
  for (int i = 0; i < NSLOT; ++i) {
    float a = dots[i] * inv;
    if (write_attn) attn_out[((size_t)b * NSLOT + i) * NTOK + j] = a;
    float ae = a + ATTN_EPS_C;
    sa[i][t] = ae;
    float ps = ae;
#pragma unroll
    for (int off = 32; off > 0; off >>= 1) ps += __shfl_down(ps, off, 64);
    if (lane == 0) partial[wid][i] = ps;
  }
  __syncthreads();  // sa, sm, srd, partial all complete
  if (t < NSLOT) {
    float s4 = partial[0][t] + partial[1][t] + partial[2][t] + partial[3][t];
    atomicAdd(&S[b * NSLOT + t], s4);
  }
  // phase 2: coalesced re-read (L2-hot tile), accumulate updates
  float gt = sg[t], bet = sbe[t];
  float acc[NSLOT] = {};
  const float* xb = X + ((size_t)(b * NTOK + j0)) * DDIM + t;
  for (int jj = 0; jj < 256; ++jj) {
    float xv = xb[(size_t)jj * DDIM];
    float xl = (xv - sm[jj]) * srd[jj] * gt + bet;
#pragma unroll
    for (int i = 0; i < NSLOT; ++i) acc[i] = fmaf(xl, sa[i][jj], acc[i]);
  }
#pragma unroll
  for (int i = 0; i < NSLOT; ++i)
    atomicAdd(&u_unnorm[((size_t)b * NSLOT + i) * DDIM + t], acc[i]);
}

// per slot row: updates = (u/S)@Wv^T + bv -> GRU -> slots' -> +MLP(LN(slots'))
// all matvecs via transposed weights (coalesced)
__global__ __launch_bounds__(256) void upd_gru_ff_k(
    const float* __restrict__ u_unnorm, const float* __restrict__ S,
    const float* __restrict__ slots_in, const float* __restrict__ WvT,
    const float* __restrict__ bv, const float* __restrict__ WihT,
    const float* __restrict__ WhhT, const float* __restrict__ b_ih,
    const float* __restrict__ b_hh, const float* __restrict__ g_ff,
    const float* __restrict__ be_ff, const float* __restrict__ W1T,
    const float* __restrict__ b1, const float* __restrict__ W2T,
    const float* __restrict__ b2, float* __restrict__ slots_out) {
  __shared__ float su[DDIM], sh[DDIM], supd[DDIM], pre[DDIM], hid[DDIM];
  __shared__ float red[8];
  int r = blockIdx.x, t = threadIdx.x;
  float invS = 1.f / S[r];
  su[t] = u_unnorm[(size_t)r * DDIM + t] * invS;
  float hval = slots_in[(size_t)r * DDIM + t];
  sh[t] = hval;
  __syncthreads();
  // updates[t] = bv[t] + sum_d su[d] * WvT[d][t]
  float upd = bv[t];
  {
    const float* p = WvT + t;
#pragma unroll 8
    for (int d = 0; d < DDIM; ++d) upd = fmaf(su[d], p[(size_t)d * DDIM], upd);
  }
  supd[t] = upd;
  __syncthreads();
  // GRU gates: WihT/WhhT are [256][768]
  float air = b_ih[t], aiz = b_ih[DDIM + t], ain = b_ih[2 * DDIM + t];
  float ahr = b_hh[t], ahz = b_hh[DDIM + t], ahn = b_hh[2 * DDIM + t];
  const float* pih = WihT + t;
  const float* phh = WhhT + t;
#pragma unroll 4
  for (int d = 0; d < DDIM; ++d) {
    float ud = supd[d], hd = sh[d];
    size_t off = (size_t)d * (3 * DDIM);
    air = fmaf(ud, pih[off], air);
    aiz = fmaf(ud, pih[off + DDIM], aiz);
    ain = fmaf(ud, pih[off + 2 * DDIM], ain);
    ahr = fmaf(hd, phh[off], ahr);
    ahz = fmaf(hd, phh[off + DDIM], ahz);
    ahn = fmaf(hd, phh[off + 2 * DDIM], ahn);
  }
  float rg = 1.f / (1.f + expf(-(air + ahr)));
  float zg = 1.f / (1.f + expf(-(aiz + ahz)));
  float ng = tanhf(ain + rg * ahn);
  float nh = (1.f - zg) * ng + zg * hval;
  // FF
  float s2 = nh, ss2 = nh * nh;
  wave_reduce2(s2, ss2);
  int lane = t & 63, wid = t >> 6;
  if (lane == 0) { red[wid] = s2; red[4 + wid] = ss2; }
  __syncthreads();
  s2 = red[0] + red[1] + red[2] + red[3];
  ss2 = red[4] + red[5] + red[6] + red[7];
  float m2 = s2 * (1.f / DDIM);
  float v2 = ss2 * (1.f / DDIM) - m2 * m2;
  float rs2 = rsqrtf(v2 + LN_EPS_C);
  pre[t] = (nh - m2) * rs2 * g_ff[t] + be_ff[t];
  __syncthreads();
  float ac1 = b1[t];
  {
    const float* p = W1T + t;
#pragma unroll 8
    for (int d = 0; d < DDIM; ++d) ac1 = fmaf(pre[d], p[(size_t)d * DDIM], ac1);
  }
  hid[t] = fmaxf(ac1, 0.f);
  __syncthreads();
  float ac2 = b2[t];
  {
    const float* p = W2T + t;
#pragma unroll 8
    for (int d = 0; d < DDIM; ++d) ac2 = fmaf(hid[d], p[(size_t)d * DDIM], ac2);
  }
  slots_out[(size_t)r * DDIM + t] = nh + ac2;
}

extern "C" void kernel_launch(void* const* d_in, const int* in_sizes, int n_in,
                              void* d_out, int out_size, void* d_ws,
                              size_t ws_size, hipStream_t stream) {
  const float* inputs   = (const float*)d_in[0];
  const float* noise    = (const float*)d_in[1];
  const float* slots_mu = (const float*)d_in[2];
  const float* slots_ls = (const float*)d_in[3];
  const float* Wq   = (const float*)d_in[4];
  const float* bq   = (const float*)d_in[5];
  const float* Wk   = (const float*)d_in[6];
  const float* bk   = (const float*)d_in[7];
  const float* Wv   = (const float*)d_in[8];
  const float* bv   = (const float*)d_in[9];
  const float* W_ih = (const float*)d_in[10];
  const float* W_hh = (const float*)d_in[11];
  const float* b_ih = (const float*)d_in[12];
  const float* b_hh = (const float*)d_in[13];
  const float* W1   = (const float*)d_in[14];
  const float* b1   = (const float*)d_in[15];
  const float* W2   = (const float*)d_in[16];
  const float* b2   = (const float*)d_in[17];
  const float* g_in = (const float*)d_in[18];
  const float* be_in= (const float*)d_in[19];
  const float* g_sl = (const float*)d_in[20];
  const float* be_sl= (const float*)d_in[21];
  const float* g_ff = (const float*)d_in[22];
  const float* be_ff= (const float*)d_in[23];

  float* out_slots = (float*)d_out;                 // [32,8,256]
  float* out_attn  = (float*)d_out + SROWS * DDIM;  // [32,8,4096]

  float* w = (float*)d_ws;
  float* slots = w;    w += SROWS * DDIM;       // 65536
  float* qk = w;       w += SROWS * DDIM;       // 65536
  float* qkb = w;      w += SROWS;              // 256
  float* S = w;        w += SROWS;              // 256
  float* u_unnorm = w; w += SROWS * DDIM;       // 65536
  float* WqT = w;      w += DDIM * DDIM;        // 65536
  float* WvT = w;      w += DDIM * DDIM;        // 65536
  float* WihT = w;     w += DDIM * 3 * DDIM;    // 196608
  float* WhhT = w;     w += DDIM * 3 * DDIM;    // 196608
  float* W1T = w;      w += DDIM * DDIM;        // 65536
  float* W2T = w;      w += DDIM * DDIM;        // 65536
  // total ~4.2 MB

  init_slots_k<<<SROWS, 256, 0, stream>>>(noise, slots_mu, slots_ls, slots);
  transpose_all_k<<<dim3(80, 8), 256, 0, stream>>>(
      Wq, Wv, W_ih, W_hh, W1, W2, WqT, WvT, WihT, WhhT, W1T, W2T);

  for (int it = 0; it < 3; ++it) {
    q_qk_k<<<SROWS, 256, 0, stream>>>(slots, g_sl, be_sl, WqT, bq, Wk, bk, qk,
                                      qkb, u_unnorm, S);
    fused_attn_k<<<dim3(NBATCH, 16), 256, 0, stream>>>(
        inputs, g_in, be_in, qk, qkb, out_attn, S, u_unnorm, (it == 2) ? 1 : 0);
    float* sout = (it == 2) ? out_slots : slots;
    upd_gru_ff_k<<<SROWS, 256, 0, stream>>>(u_unnorm, S, slots, WvT, bv, WihT,
                                            WhhT, b_ih, b_hh, g_ff, be_ff, W1T,
                                            b1, W2T, b2, sout);
  }
}

// Round 4
// 470.530 us; speedup vs baseline: 1.0579x; 1.0366x over previous
//
#include <hip/hip_runtime.h>
#include <hip/hip_fp16.h>
#include <cstdint>
#include <cstddef>

// SlotAttention fused fp32, round 3.
//  - fused_attn: 64-token chunks (2048 blocks, ~7 blocks/CU), single x-pass for
//    stats+dots via dots = rs*(P1 - m*G) + C0; softmax in wave 0; u-partials
//    plain-stored as fp16 (no atomics).
//  - slot path: one kernel doing u-reduce -> Wv -> GRU -> FF -> (LN -> q -> qk,
//    G, C0) for the next iteration. init variant seeds slots from noise.

#define NTOK 4096
#define DDIM 256
#define NSLOT 8
#define NBATCH 32
#define NCHUNK 64               // tokens per fused block
#define NCHK (NTOK / NCHUNK)    // 64 chunks per batch
#define SROWS (NBATCH * NSLOT)  // 256 slot rows
#define SCALE 0.0625f
#define LN_EPS_C 1e-5f
#define ATTN_EPS_C 1e-8f

__device__ __forceinline__ void wave_reduce2(float& s, float& ss) {
#pragma unroll
  for (int off = 32; off > 0; off >>= 1) {
    s  += __shfl_down(s, off, 64);
    ss += __shfl_down(ss, off, 64);
  }
}
__device__ __forceinline__ void wave_reduce3(float& a, float& b, float& c) {
#pragma unroll
  for (int off = 32; off > 0; off >>= 1) {
    a += __shfl_down(a, off, 64);
    b += __shfl_down(b, off, 64);
    c += __shfl_down(c, off, 64);
  }
}

// One launch transposing all six weight matrices (row 2 version, verified).
__global__ __launch_bounds__(256) void transpose_all_k(
    const float* __restrict__ Wq, const float* __restrict__ Wv,
    const float* __restrict__ Wih, const float* __restrict__ Whh,
    const float* __restrict__ W1, const float* __restrict__ W2,
    float* __restrict__ WqT, float* __restrict__ WvT,
    float* __restrict__ WihT, float* __restrict__ WhhT,
    float* __restrict__ W1T, float* __restrict__ W2T) {
  __shared__ float tile[32][33];
  int bz = blockIdx.x;
  const float* in; float* out; int O, bo;
  if (bz < 8)       { in = Wq;  out = WqT;  O = 256; bo = bz; }
  else if (bz < 16) { in = Wv;  out = WvT;  O = 256; bo = bz - 8; }
  else if (bz < 40) { in = Wih; out = WihT; O = 768; bo = bz - 16; }
  else if (bz < 64) { in = Whh; out = WhhT; O = 768; bo = bz - 40; }
  else if (bz < 72) { in = W1;  out = W1T;  O = 256; bo = bz - 64; }
  else              { in = W2;  out = W2T;  O = 256; bo = bz - 72; }
  int tx = threadIdx.x & 31, ty = threadIdx.x >> 5;
  int ro = bo * 32, cd = blockIdx.y * 32;
#pragma unroll
  for (int p = 0; p < 32; p += 8)
    tile[ty + p][tx] = in[(size_t)(ro + ty + p) * DDIM + cd + tx];
  __syncthreads();
#pragma unroll
  for (int p = 0; p < 32; p += 8)
    out[(size_t)(cd + ty + p) * O + ro + tx] = tile[tx][ty + p];
}

// shared tail: newslot row -> LN -> q -> qk (SCALE folded) + per-row G, C0.
// ln/sq are caller-provided 256-float LDS arrays; red has >= 12 floats.
__device__ __forceinline__ void qk_tail(
    float newslot, int r, int t, const float* __restrict__ g_sl,
    const float* __restrict__ be_sl, const float* __restrict__ WqT,
    const float* __restrict__ bq, const float* __restrict__ Wk,
    const float* __restrict__ bk, const float* __restrict__ g_in,
    const float* __restrict__ be_in, float* __restrict__ qk,
    float* __restrict__ C0, float* __restrict__ G, float* ln, float* sq,
    float* red) {
  float s = newslot, ss = newslot * newslot;
  wave_reduce2(s, ss);
  int lane = t & 63, wid = t >> 6;
  if (lane == 0) { red[wid] = s; red[4 + wid] = ss; }
  __syncthreads();
  s = red[0] + red[1] + red[2] + red[3];
  ss = red[4] + red[5] + red[6] + red[7];
  float m = s * (1.f / DDIM);
  float rs = rsqrtf(ss * (1.f / DDIM) - m * m + LN_EPS_C);
  ln[t] = (newslot - m) * rs * g_sl[t] + be_sl[t];
  __syncthreads();
  float q = bq[t];
  {
    const float* p = WqT + t;
#pragma unroll 8
    for (int d = 0; d < DDIM; ++d) q = fmaf(ln[d], p[(size_t)d * DDIM], q);
  }
  sq[t] = q;
  __syncthreads();
  float a2 = 0.f;
  {
    const float* p = Wk + t;
#pragma unroll 8
    for (int o = 0; o < DDIM; ++o) a2 = fmaf(sq[o], p[(size_t)o * DDIM], a2);
  }
  float qkv = SCALE * a2;
  qk[(size_t)r * DDIM + t] = qkv;
  float v0 = q * bk[t], v1 = g_in[t] * qkv, v2 = be_in[t] * qkv;
  wave_reduce3(v0, v1, v2);
  __syncthreads();
  if (lane == 0) { red[wid] = v0; red[4 + wid] = v1; red[8 + wid] = v2; }
  __syncthreads();
  if (t == 0) {
    float qkb = SCALE * (red[0] + red[1] + red[2] + red[3]);
    float Gv = red[4] + red[5] + red[6] + red[7];
    float Bv = red[8] + red[9] + red[10] + red[11];
    C0[r] = qkb + Bv;
    G[r] = Gv;
  }
}

// iteration 0 seed: slots from noise; then qk/G/C0; zero S.
__global__ __launch_bounds__(256) void init_q_qk_k(
    const float* __restrict__ noise, const float* __restrict__ mu,
    const float* __restrict__ logsig, float* __restrict__ slots,
    const float* __restrict__ g_sl, const float* __restrict__ be_sl,
    const float* __restrict__ WqT, const float* __restrict__ bq,
    const float* __restrict__ Wk, const float* __restrict__ bk,
    const float* __restrict__ g_in, const float* __restrict__ be_in,
    float* __restrict__ qk, float* __restrict__ C0, float* __restrict__ G,
    float* __restrict__ S) {
  __shared__ float ln[DDIM], sq[DDIM], red[12];
  int r = blockIdx.x, t = threadIdx.x;
  float ns = mu[t] + expf(logsig[t]) * noise[(size_t)r * DDIM + t];
  slots[(size_t)r * DDIM + t] = ns;
  if (t == 0) S[r] = 0.f;
  qk_tail(ns, r, t, g_sl, be_sl, WqT, bq, Wk, bk, g_in, be_in, qk, C0, G, ln,
          sq, red);
}

// fused per-iteration token pass. Block = (batch b, chunk c of 64 tokens).
// thread t: token tj = t&63, dim-quarter qd = t>>6.
//  phase A: single x read -> s/ss/P1[8] partials (qk reads are wave-broadcast)
//  phase B (wave 0): reduce, LN stats, dots, softmax, attn write (last iter),
//           sa = attn+eps, S partial atomics
//  phase C: thread=dim, u partial over 64 tokens -> fp16 plain store
__global__ __launch_bounds__(256) void fused_attn_k(
    const float* __restrict__ X, const float* __restrict__ g,
    const float* __restrict__ be, const float* __restrict__ qk,
    const float* __restrict__ C0, const float* __restrict__ G,
    float* __restrict__ attn_out, float* __restrict__ S,
    __half* __restrict__ u_part, int write_attn) {
  __shared__ float sqkg[NSLOT][DDIM];          // qk * g
  __shared__ float pd[4][NSLOT][NCHUNK];       // P1 partials
  __shared__ float pss[2][4][NCHUNK];          // s/ss partials
  __shared__ float sa[NSLOT][NCHUNK];          // attn + eps
  __shared__ float sm[NCHUNK], srd[NCHUNK];
  int b = blockIdx.x, c = blockIdx.y, t = threadIdx.x;
  int tj = t & 63, qd = t >> 6;
#pragma unroll
  for (int i = 0; i < NSLOT; ++i)
    sqkg[i][t] = qk[((size_t)b * NSLOT + i) * DDIM + t] * g[t];
  __syncthreads();
  const float* xr =
      X + ((size_t)(b * NTOK + c * NCHUNK + tj)) * DDIM + qd * 64;
  float s = 0.f, ss = 0.f, p[NSLOT] = {};
#pragma unroll
  for (int dd = 0; dd < 64; dd += 4) {
    float4 xv = *(const float4*)(xr + dd);
    s += xv.x + xv.y + xv.z + xv.w;
    ss += xv.x * xv.x + xv.y * xv.y + xv.z * xv.z + xv.w * xv.w;
    int d0 = qd * 64 + dd;
#pragma unroll
    for (int i = 0; i < NSLOT; ++i) {
      float4 qv = *(const float4*)&sqkg[i][d0];  // wave-uniform -> broadcast
      p[i] += xv.x * qv.x + xv.y * qv.y + xv.z * qv.z + xv.w * qv.w;
    }
  }
  pss[0][qd][tj] = s;
  pss[1][qd][tj] = ss;
#pragma unroll
  for (int i = 0; i < NSLOT; ++i) pd[qd][i][tj] = p[i];
  __syncthreads();
  if (t < NCHUNK) {
    float s1 = pss[0][0][tj] + pss[0][1][tj] + pss[0][2][tj] + pss[0][3][tj];
    float s2 = pss[1][0][tj] + pss[1][1][tj] + pss[1][2][tj] + pss[1][3][tj];
    float m = s1 * (1.f / DDIM);
    float rs = rsqrtf(s2 * (1.f / DDIM) - m * m + LN_EPS_C);
    sm[tj] = m;
    srd[tj] = rs;
    float dots[NSLOT], mx = -1e30f;
#pragma unroll
    for (int i = 0; i < NSLOT; ++i) {
      float P1 = pd[0][i][tj] + pd[1][i][tj] + pd[2][i][tj] + pd[3][i][tj];
      dots[i] = rs * (P1 - m * G[b * NSLOT + i]) + C0[b * NSLOT + i];
      mx = fmaxf(mx, dots[i]);
    }
    float sum = 0.f;
#pragma unroll
    for (int i = 0; i < NSLOT; ++i) {
      dots[i] = expf(dots[i] - mx);
      sum += dots[i];
    }
    float inv = 1.f / sum;
#pragma unroll
    for (int i = 0; i < NSLOT; ++i) {
      float a = dots[i] * inv;
      if (write_attn)
        attn_out[((size_t)b * NSLOT + i) * NTOK + c * NCHUNK + tj] = a;
      float ae = a + ATTN_EPS_C;
      sa[i][tj] = ae;
      float ps = ae;
#pragma unroll
      for (int off = 32; off > 0; off >>= 1) ps += __shfl_down(ps, off, 64);
      if (tj == 0) atomicAdd(&S[b * NSLOT + i], ps);
    }
  }
  __syncthreads();
  // phase C: thread = dim t; x re-read is coalesced and L1/L2-hot
  float gt = g[t], bet = be[t];
  float acc[NSLOT] = {};
  const float* xc = X + ((size_t)(b * NTOK + c * NCHUNK)) * DDIM + t;
  for (int jj = 0; jj < NCHUNK; ++jj) {
    float xv = xc[(size_t)jj * DDIM];
    float xl = (xv - sm[jj]) * srd[jj] * gt + bet;
#pragma unroll
    for (int i = 0; i < NSLOT; ++i) acc[i] = fmaf(xl, sa[i][jj], acc[i]);
  }
  __half* upb = u_part + (((size_t)b * NCHK + c) * NSLOT) * DDIM + t;
#pragma unroll
  for (int i = 0; i < NSLOT; ++i) upb[(size_t)i * DDIM] = __float2half(acc[i]);
}

// slot path: u reduce -> /S -> Wv -> GRU -> FF; optionally qk for next iter.
__global__ __launch_bounds__(256) void slot_update_k(
    const __half* __restrict__ u_part, float* __restrict__ S,
    const float* __restrict__ slots_in, const float* __restrict__ WvT,
    const float* __restrict__ bv, const float* __restrict__ WihT,
    const float* __restrict__ WhhT, const float* __restrict__ b_ih,
    const float* __restrict__ b_hh, const float* __restrict__ g_ff,
    const float* __restrict__ be_ff, const float* __restrict__ W1T,
    const float* __restrict__ b1, const float* __restrict__ W2T,
    const float* __restrict__ b2, const float* __restrict__ g_sl,
    const float* __restrict__ be_sl, const float* __restrict__ WqT,
    const float* __restrict__ bq, const float* __restrict__ Wk,
    const float* __restrict__ bk, const float* __restrict__ g_in,
    const float* __restrict__ be_in, float* __restrict__ slots_out,
    float* __restrict__ qk, float* __restrict__ C0, float* __restrict__ G,
    int compute_qk) {
  __shared__ float su[DDIM], sh[DDIM], supd[DDIM], pre[DDIM], hid[DDIM];
  __shared__ float red[12];
  int r = blockIdx.x, t = threadIdx.x;
  int b = r >> 3, i = r & 7;
  float u = 0.f;
  const __half* up = u_part + ((size_t)b * NCHK * NSLOT + i) * DDIM + t;
#pragma unroll 8
  for (int g2 = 0; g2 < NCHK; ++g2)
    u += __half2float(up[(size_t)g2 * (NSLOT * DDIM)]);
  float invS = 1.f / S[r];
  su[t] = u * invS;
  float hval = slots_in[(size_t)r * DDIM + t];
  sh[t] = hval;
  __syncthreads();
  if (t == 0) S[r] = 0.f;  // ready for next fused iteration
  float upd = bv[t];
  {
    const float* p = WvT + t;
#pragma unroll 8
    for (int d = 0; d < DDIM; ++d) upd = fmaf(su[d], p[(size_t)d * DDIM], upd);
  }
  supd[t] = upd;
  __syncthreads();
  float air = b_ih[t], aiz = b_ih[DDIM + t], ain = b_ih[2 * DDIM + t];
  float ahr = b_hh[t], ahz = b_hh[DDIM + t], ahn = b_hh[2 * DDIM + t];
  const float* pih = WihT + t;
  const float* phh = WhhT + t;
#pragma unroll 4
  for (int d = 0; d < DDIM; ++d) {
    float ud = supd[d], hd = sh[d];
    size_t off = (size_t)d * (3 * DDIM);
    air = fmaf(ud, pih[off], air);
    aiz = fmaf(ud, pih[off + DDIM], aiz);
    ain = fmaf(ud, pih[off + 2 * DDIM], ain);
    ahr = fmaf(hd, phh[off], ahr);
    ahz = fmaf(hd, phh[off + DDIM], ahz);
    ahn = fmaf(hd, phh[off + 2 * DDIM], ahn);
  }
  float rg = 1.f / (1.f + expf(-(air + ahr)));
  float zg = 1.f / (1.f + expf(-(aiz + ahz)));
  float ng = tanhf(ain + rg * ahn);
  float nh = (1.f - zg) * ng + zg * hval;
  // FF
  float s2 = nh, ss2 = nh * nh;
  wave_reduce2(s2, ss2);
  int lane = t & 63, wid = t >> 6;
  if (lane == 0) { red[wid] = s2; red[4 + wid] = ss2; }
  __syncthreads();
  s2 = red[0] + red[1] + red[2] + red[3];
  ss2 = red[4] + red[5] + red[6] + red[7];
  float m2 = s2 * (1.f / DDIM);
  float rs2 = rsqrtf(ss2 * (1.f / DDIM) - m2 * m2 + LN_EPS_C);
  pre[t] = (nh - m2) * rs2 * g_ff[t] + be_ff[t];
  __syncthreads();
  float ac1 = b1[t];
  {
    const float* p = W1T + t;
#pragma unroll 8
    for (int d = 0; d < DDIM; ++d) ac1 = fmaf(pre[d], p[(size_t)d * DDIM], ac1);
  }
  hid[t] = fmaxf(ac1, 0.f);
  __syncthreads();
  float ac2 = b2[t];
  {
    const float* p = W2T + t;
#pragma unroll 8
    for (int d = 0; d < DDIM; ++d) ac2 = fmaf(hid[d], p[(size_t)d * DDIM], ac2);
  }
  float out = nh + ac2;
  slots_out[(size_t)r * DDIM + t] = out;
  if (compute_qk)
    qk_tail(out, r, t, g_sl, be_sl, WqT, bq, Wk, bk, g_in, be_in, qk, C0, G,
            pre, hid, red);
}

extern "C" void kernel_launch(void* const* d_in, const int* in_sizes, int n_in,
                              void* d_out, int out_size, void* d_ws,
                              size_t ws_size, hipStream_t stream) {
  const float* inputs   = (const float*)d_in[0];
  const float* noise    = (const float*)d_in[1];
  const float* slots_mu = (const float*)d_in[2];
  const float* slots_ls = (const float*)d_in[3];
  const float* Wq   = (const float*)d_in[4];
  const float* bq   = (const float*)d_in[5];
  const float* Wk   = (const float*)d_in[6];
  const float* bk   = (const float*)d_in[7];
  const float* Wv   = (const float*)d_in[8];
  const float* bv   = (const float*)d_in[9];
  const float* W_ih = (const float*)d_in[10];
  const float* W_hh = (const float*)d_in[11];
  const float* b_ih = (const float*)d_in[12];
  const float* b_hh = (const float*)d_in[13];
  const float* W1   = (const float*)d_in[14];
  const float* b1   = (const float*)d_in[15];
  const float* W2   = (const float*)d_in[16];
  const float* b2   = (const float*)d_in[17];
  const float* g_in = (const float*)d_in[18];
  const float* be_in= (const float*)d_in[19];
  const float* g_sl = (const float*)d_in[20];
  const float* be_sl= (const float*)d_in[21];
  const float* g_ff = (const float*)d_in[22];
  const float* be_ff= (const float*)d_in[23];

  float* out_slots = (float*)d_out;                 // [32,8,256]
  float* out_attn  = (float*)d_out + SROWS * DDIM;  // [32,8,4096]

  float* w = (float*)d_ws;
  float* slots = w; w += SROWS * DDIM;
  float* qk = w;    w += SROWS * DDIM;
  float* C0 = w;    w += SROWS;
  float* G = w;     w += SROWS;
  float* S = w;     w += SROWS;
  float* WqT = w;   w += DDIM * DDIM;
  float* WvT = w;   w += DDIM * DDIM;
  float* WihT = w;  w += DDIM * 3 * DDIM;
  float* WhhT = w;  w += DDIM * 3 * DDIM;
  float* W1T = w;   w += DDIM * DDIM;
  float* W2T = w;   w += DDIM * DDIM;
  __half* u_part = (__half*)w;  // [32][64][8][256] fp16 = 8 MB
  // total ws ~ 10.9 MB

  transpose_all_k<<<dim3(80, 8), 256, 0, stream>>>(
      Wq, Wv, W_ih, W_hh, W1, W2, WqT, WvT, WihT, WhhT, W1T, W2T);
  init_q_qk_k<<<SROWS, 256, 0, stream>>>(noise, slots_mu, slots_ls, slots,
                                         g_sl, be_sl, WqT, bq, Wk, bk, g_in,
                                         be_in, qk, C0, G, S);
  for (int it = 0; it < 3; ++it) {
    fused_attn_k<<<dim3(NBATCH, NCHK), 256, 0, stream>>>(
        inputs, g_in, be_in, qk, C0, G, out_attn, S, u_part,
        (it == 2) ? 1 : 0);
    float* sout = (it == 2) ? out_slots : slots;
    slot_update_k<<<SROWS, 256, 0, stream>>>(
        u_part, S, slots, WvT, bv, WihT, WhhT, b_ih, b_hh, g_ff, be_ff, W1T,
        b1, W2T, b2, g_sl, be_sl, WqT, bq, Wk, bk, g_in, be_in, sout, qk, C0,
        G, (it == 2) ? 0 : 1);
  }
}

// Round 5
// 284.192 us; speedup vs baseline: 1.7516x; 1.6557x over previous
//
#include <hip/hip_runtime.h>
#include <hip/hip_fp16.h>
#include <cstdint>
#include <cstddef>

// SlotAttention fused fp32, round 4.
//  - fused_attn: LDS-staged fp32 X-tile (coalesced float4 loads), two 32-token
//    halves per block; dots via dots = rs*(P1 - m*G) + C0; atomic-free
//    (per-block S partials); u partials fp16 plain-stored.
//  - slot_update: 1024 threads, k-split x4 + LDS reduction for every matvec
//    in the chain u->Wv->GRU->FF->(LN->q->qk,G,C0). 16 waves/CU vs 4 before.

#define NTOK 4096
#define DDIM 256
#define NSLOT 8
#define NBATCH 32
#define NCHK 64                 // 64-token chunks (2 halves of 32)
#define SROWS (NBATCH * NSLOT)  // 256 slot rows
#define SCALE 0.0625f
#define LN_EPS_C 1e-5f
#define ATTN_EPS_C 1e-8f

__device__ __forceinline__ void wave_reduce2(float& s, float& ss) {
#pragma unroll
  for (int off = 32; off > 0; off >>= 1) {
    s  += __shfl_down(s, off, 64);
    ss += __shfl_down(ss, off, 64);
  }
}
__device__ __forceinline__ void wave_reduce3(float& a, float& b, float& c) {
#pragma unroll
  for (int off = 32; off > 0; off >>= 1) {
    a += __shfl_down(a, off, 64);
    b += __shfl_down(b, off, 64);
    c += __shfl_down(c, off, 64);
  }
}

// One launch transposing all six weight matrices (verified round 2/3).
__global__ __launch_bounds__(256) void transpose_all_k(
    const float* __restrict__ Wq, const float* __restrict__ Wv,
    const float* __restrict__ Wih, const float* __restrict__ Whh,
    const float* __restrict__ W1, const float* __restrict__ W2,
    float* __restrict__ WqT, float* __restrict__ WvT,
    float* __restrict__ WihT, float* __restrict__ WhhT,
    float* __restrict__ W1T, float* __restrict__ W2T) {
  __shared__ float tile[32][33];
  int bz = blockIdx.x;
  const float* in; float* out; int O, bo;
  if (bz < 8)       { in = Wq;  out = WqT;  O = 256; bo = bz; }
  else if (bz < 16) { in = Wv;  out = WvT;  O = 256; bo = bz - 8; }
  else if (bz < 40) { in = Wih; out = WihT; O = 768; bo = bz - 16; }
  else if (bz < 64) { in = Whh; out = WhhT; O = 768; bo = bz - 40; }
  else if (bz < 72) { in = W1;  out = W1T;  O = 256; bo = bz - 64; }
  else              { in = W2;  out = W2T;  O = 256; bo = bz - 72; }
  int tx = threadIdx.x & 31, ty = threadIdx.x >> 5;
  int ro = bo * 32, cd = blockIdx.y * 32;
#pragma unroll
  for (int p = 0; p < 32; p += 8)
    tile[ty + p][tx] = in[(size_t)(ro + ty + p) * DDIM + cd + tx];
  __syncthreads();
#pragma unroll
  for (int p = 0; p < 32; p += 8)
    out[(size_t)(cd + ty + p) * O + ro + tx] = tile[tx][ty + p];
}

// init-time tail (256 threads, serial matvecs — one-shot, verified round 3):
// newslot -> LN -> q -> qk (SCALE folded) + per-row G, C0.
__device__ __forceinline__ void qk_tail(
    float newslot, int r, int t, const float* __restrict__ g_sl,
    const float* __restrict__ be_sl, const float* __restrict__ WqT,
    const float* __restrict__ bq, const float* __restrict__ Wk,
    const float* __restrict__ bk, const float* __restrict__ g_in,
    const float* __restrict__ be_in, float* __restrict__ qk,
    float* __restrict__ C0, float* __restrict__ G, float* ln, float* sq,
    float* red) {
  float s = newslot, ss = newslot * newslot;
  wave_reduce2(s, ss);
  int lane = t & 63, wid = t >> 6;
  if (lane == 0) { red[wid] = s; red[4 + wid] = ss; }
  __syncthreads();
  s = red[0] + red[1] + red[2] + red[3];
  ss = red[4] + red[5] + red[6] + red[7];
  float m = s * (1.f / DDIM);
  float rs = rsqrtf(ss * (1.f / DDIM) - m * m + LN_EPS_C);
  ln[t] = (newslot - m) * rs * g_sl[t] + be_sl[t];
  __syncthreads();
  float q = bq[t];
  {
    const float* p = WqT + t;
#pragma unroll 8
    for (int d = 0; d < DDIM; ++d) q = fmaf(ln[d], p[(size_t)d * DDIM], q);
  }
  sq[t] = q;
  __syncthreads();
  float a2 = 0.f;
  {
    const float* p = Wk + t;
#pragma unroll 8
    for (int o = 0; o < DDIM; ++o) a2 = fmaf(sq[o], p[(size_t)o * DDIM], a2);
  }
  float qkv = SCALE * a2;
  qk[(size_t)r * DDIM + t] = qkv;
  float v0 = q * bk[t], v1 = g_in[t] * qkv, v2 = be_in[t] * qkv;
  wave_reduce3(v0, v1, v2);
  __syncthreads();
  if (lane == 0) { red[wid] = v0; red[4 + wid] = v1; red[8 + wid] = v2; }
  __syncthreads();
  if (t == 0) {
    float qkb = SCALE * (red[0] + red[1] + red[2] + red[3]);
    float Gv = red[4] + red[5] + red[6] + red[7];
    float Bv = red[8] + red[9] + red[10] + red[11];
    C0[r] = qkb + Bv;
    G[r] = Gv;
  }
}

__global__ __launch_bounds__(256) void init_q_qk_k(
    const float* __restrict__ noise, const float* __restrict__ mu,
    const float* __restrict__ logsig, float* __restrict__ slots,
    const float* __restrict__ g_sl, const float* __restrict__ be_sl,
    const float* __restrict__ WqT, const float* __restrict__ bq,
    const float* __restrict__ Wk, const float* __restrict__ bk,
    const float* __restrict__ g_in, const float* __restrict__ be_in,
    float* __restrict__ qk, float* __restrict__ C0, float* __restrict__ G) {
  __shared__ float ln[DDIM], sq[DDIM], red[12];
  int r = blockIdx.x, t = threadIdx.x;
  float ns = mu[t] + expf(logsig[t]) * noise[(size_t)r * DDIM + t];
  slots[(size_t)r * DDIM + t] = ns;
  qk_tail(ns, r, t, g_sl, be_sl, WqT, bq, Wk, bk, g_in, be_in, qk, C0, G, ln,
          sq, red);
}

// Per-iteration token pass. Block = (batch b, 64-token chunk c), 256 threads.
// Two 32-token halves; per half:
//  stage: X tile -> LDS (float4, coalesced)
//  A (thread = token tj, 32-dim slice qd): s/ss/P1 partials from LDS
//  B (t<32): LN stats, dots = rs*(P1-m*G)+C0, softmax, S partial, sa
//  C (thread = dim): u accumulation from LDS tile
__global__ __launch_bounds__(256) void fused_attn_k(
    const float* __restrict__ X, const float* __restrict__ g,
    const float* __restrict__ be, const float* __restrict__ qk,
    const float* __restrict__ C0, const float* __restrict__ Gv,
    float* __restrict__ attn_out, float* __restrict__ S_part,
    __half* __restrict__ u_part, int write_attn) {
  __shared__ float sx[32][260];        // fp32 tile, 16B-aligned rows
  __shared__ float sqkg[NSLOT][DDIM];  // qk * g
  __shared__ float part[8][10][32];    // [slice][8 slots + s + ss][token]
  __shared__ float sm[32], srd[32];
  __shared__ float sC0[NSLOT], sG[NSLOT], sS[NSLOT];
  int b = blockIdx.x, c = blockIdx.y, t = threadIdx.x;
  int tj = t & 31, qd = t >> 5;
#pragma unroll
  for (int i = 0; i < NSLOT; ++i)
    sqkg[i][t] = qk[((size_t)b * NSLOT + i) * DDIM + t] * g[t];
  if (t < NSLOT) { sC0[t] = C0[b * NSLOT + t]; sG[t] = Gv[b * NSLOT + t]; sS[t] = 0.f; }
  float gt = g[t], bet = be[t];
  float acc[NSLOT] = {};
  const size_t base = (size_t)b * NTOK + (size_t)c * 64;
#pragma unroll
  for (int half = 0; half < 2; ++half) {
    __syncthreads();  // sC0/sS ready (first); prev phase C done (second)
    // stage
#pragma unroll
    for (int it = 0; it < 8; ++it) {
      int e = it * 256 + t;
      int row = e >> 6, c4 = e & 63;
      float4 v = *(const float4*)(X + (base + half * 32 + row) * DDIM + c4 * 4);
      *(float4*)&sx[row][c4 * 4] = v;
    }
    __syncthreads();
    // phase A
    float s = 0.f, ss = 0.f, p[NSLOT] = {};
#pragma unroll
    for (int d4 = 0; d4 < 8; ++d4) {
      float4 xv = *(const float4*)&sx[tj][qd * 32 + d4 * 4];
      s += xv.x + xv.y + xv.z + xv.w;
      ss += xv.x * xv.x + xv.y * xv.y + xv.z * xv.z + xv.w * xv.w;
#pragma unroll
      for (int i = 0; i < NSLOT; ++i) {
        float4 qv = *(const float4*)&sqkg[i][qd * 32 + d4 * 4];
        p[i] += xv.x * qv.x + xv.y * qv.y + xv.z * qv.z + xv.w * qv.w;
      }
    }
#pragma unroll
    for (int i = 0; i < NSLOT; ++i) part[qd][i][tj] = p[i];
    part[qd][8][tj] = s;
    part[qd][9][tj] = ss;
    __syncthreads();
    // phase B (wave 0, lanes 0..31)
    if (t < 32) {
      float s1 = 0.f, s2 = 0.f;
#pragma unroll
      for (int q2 = 0; q2 < 8; ++q2) { s1 += part[q2][8][t]; s2 += part[q2][9][t]; }
      float m = s1 * (1.f / DDIM);
      float rs = rsqrtf(s2 * (1.f / DDIM) - m * m + LN_EPS_C);
      sm[t] = m;
      srd[t] = rs;
      float dots[NSLOT], mx = -1e30f;
#pragma unroll
      for (int i = 0; i < NSLOT; ++i) {
        float P1 = 0.f;
#pragma unroll
        for (int q2 = 0; q2 < 8; ++q2) P1 += part[q2][i][t];
        dots[i] = rs * (P1 - m * sG[i]) + sC0[i];
        mx = fmaxf(mx, dots[i]);
      }
      float sum = 0.f;
#pragma unroll
      for (int i = 0; i < NSLOT; ++i) { dots[i] = expf(dots[i] - mx); sum += dots[i]; }
      float inv = 1.f / sum;
#pragma unroll
      for (int i = 0; i < NSLOT; ++i) {
        float a = dots[i] * inv;
        if (write_attn)
          attn_out[((size_t)b * NSLOT + i) * NTOK + c * 64 + half * 32 + t] = a;
        float ae = a + ATTN_EPS_C;
        part[i][8][t] = ae;  // sa[i][token] (s/ss partials already consumed)
        float ps = ae;
#pragma unroll
        for (int off = 16; off > 0; off >>= 1) ps += __shfl_down(ps, off, 64);
        if (t == 0) sS[i] += ps;
      }
    }
    __syncthreads();
    // phase C (thread = dim t)
#pragma unroll 8
    for (int jj = 0; jj < 32; ++jj) {
      float x = sx[jj][t];
      float xl = (x - sm[jj]) * srd[jj] * gt + bet;
#pragma unroll
      for (int i = 0; i < NSLOT; ++i) acc[i] = fmaf(xl, part[i][8][jj], acc[i]);
    }
  }
  __half* upb = u_part + (((size_t)b * NCHK + c) * NSLOT) * DDIM + t;
#pragma unroll
  for (int i = 0; i < NSLOT; ++i) upb[(size_t)i * DDIM] = __float2half(acc[i]);
  if (t < NSLOT) S_part[((size_t)b * NCHK + c) * NSLOT + t] = sS[t];
}

// slot path, 1024 threads: o = t&255 (output dim), ks = t>>8 (k-slice).
// Every matvec: k-split x4 partials -> LDS -> finalize by ks==0 waves.
__global__ __launch_bounds__(1024) void slot_update_k(
    const __half* __restrict__ u_part, const float* __restrict__ S_part,
    const float* __restrict__ slots_in, const float* __restrict__ WvT,
    const float* __restrict__ bv, const float* __restrict__ WihT,
    const float* __restrict__ WhhT, const float* __restrict__ b_ih,
    const float* __restrict__ b_hh, const float* __restrict__ g_ff,
    const float* __restrict__ be_ff, const float* __restrict__ W1T,
    const float* __restrict__ b1, const float* __restrict__ W2T,
    const float* __restrict__ b2, const float* __restrict__ g_sl,
    const float* __restrict__ be_sl, const float* __restrict__ WqT,
    const float* __restrict__ bq, const float* __restrict__ Wk,
    const float* __restrict__ bk, const float* __restrict__ g_in,
    const float* __restrict__ be_in, float* __restrict__ slots_out,
    float* __restrict__ qk, float* __restrict__ C0, float* __restrict__ G,
    int compute_qk) {
  __shared__ float red[4][6][DDIM];
  __shared__ float su[DDIM], sh[DDIM], supd[DDIM], v1[DDIM], v2[DDIM];
  __shared__ float scal[16];
  int r = blockIdx.x, t = threadIdx.x;
  int b = r >> 3, i = r & 7;
  int o = t & 255, ks = t >> 8;
  int lane = t & 63, wid = t >> 6;
  // phase 0: u partials + S reduce + h load
  {
    float up = 0.f;
    const __half* upp =
        u_part + (((size_t)b * NCHK + ks * 16) * NSLOT + i) * DDIM + o;
#pragma unroll
    for (int cc = 0; cc < 16; ++cc)
      up += __half2float(upp[(size_t)cc * (NSLOT * DDIM)]);
    red[ks][0][o] = up;
  }
  if (t < 64) {
    float sp = S_part[((size_t)b * NCHK + t) * NSLOT + i];
#pragma unroll
    for (int off = 32; off > 0; off >>= 1) sp += __shfl_down(sp, off, 64);
    if (t == 0) scal[0] = sp;
  }
  if (ks == 0) sh[o] = slots_in[(size_t)r * DDIM + o];
  __syncthreads();
  if (ks == 0) {
    float invS = 1.f / scal[0];
    su[o] = (red[0][0][o] + red[1][0][o] + red[2][0][o] + red[3][0][o]) * invS;
  }
  __syncthreads();
  // phase 1: Wv
  {
    float p = 0.f;
    const float* wp = WvT + (size_t)(ks * 64) * DDIM + o;
#pragma unroll 8
    for (int dd = 0; dd < 64; ++dd)
      p = fmaf(su[ks * 64 + dd], wp[(size_t)dd * DDIM], p);
    red[ks][0][o] = p;
  }
  __syncthreads();
  if (ks == 0)
    supd[o] = bv[o] + red[0][0][o] + red[1][0][o] + red[2][0][o] + red[3][0][o];
  __syncthreads();
  // phase 2: GRU (6 matvecs)
  {
    float p0 = 0, p1 = 0, p2 = 0, p3 = 0, p4 = 0, p5 = 0;
    const float* pi = WihT + (size_t)(ks * 64) * (3 * DDIM) + o;
    const float* ph = WhhT + (size_t)(ks * 64) * (3 * DDIM) + o;
#pragma unroll 4
    for (int dd = 0; dd < 64; ++dd) {
      float ud = supd[ks * 64 + dd], hd = sh[ks * 64 + dd];
      size_t off = (size_t)dd * (3 * DDIM);
      p0 = fmaf(ud, pi[off], p0);
      p1 = fmaf(ud, pi[off + DDIM], p1);
      p2 = fmaf(ud, pi[off + 2 * DDIM], p2);
      p3 = fmaf(hd, ph[off], p3);
      p4 = fmaf(hd, ph[off + DDIM], p4);
      p5 = fmaf(hd, ph[off + 2 * DDIM], p5);
    }
    red[ks][0][o] = p0; red[ks][1][o] = p1; red[ks][2][o] = p2;
    red[ks][3][o] = p3; red[ks][4][o] = p4; red[ks][5][o] = p5;
  }
  __syncthreads();
  if (ks == 0) {
    float air = b_ih[o] + red[0][0][o] + red[1][0][o] + red[2][0][o] + red[3][0][o];
    float aiz = b_ih[DDIM + o] + red[0][1][o] + red[1][1][o] + red[2][1][o] + red[3][1][o];
    float ain = b_ih[2 * DDIM + o] + red[0][2][o] + red[1][2][o] + red[2][2][o] + red[3][2][o];
    float ahr = b_hh[o] + red[0][3][o] + red[1][3][o] + red[2][3][o] + red[3][3][o];
    float ahz = b_hh[DDIM + o] + red[0][4][o] + red[1][4][o] + red[2][4][o] + red[3][4][o];
    float ahn = b_hh[2 * DDIM + o] + red[0][5][o] + red[1][5][o] + red[2][5][o] + red[3][5][o];
    float rg = 1.f / (1.f + expf(-(air + ahr)));
    float zg = 1.f / (1.f + expf(-(aiz + ahz)));
    float ng = tanhf(ain + rg * ahn);
    float nh = (1.f - zg) * ng + zg * sh[o];
    v1[o] = nh;
    float s2 = nh, ss2 = nh * nh;
    wave_reduce2(s2, ss2);
    if (lane == 0) { scal[wid] = s2; scal[4 + wid] = ss2; }
  }
  __syncthreads();
  if (ks == 0) {
    float sS = scal[0] + scal[1] + scal[2] + scal[3];
    float sQ = scal[4] + scal[5] + scal[6] + scal[7];
    float m = sS * (1.f / DDIM);
    float rs = rsqrtf(sQ * (1.f / DDIM) - m * m + LN_EPS_C);
    v2[o] = (v1[o] - m) * rs * g_ff[o] + be_ff[o];
  }
  __syncthreads();
  // phase 3: W1 + relu
  {
    float p = 0.f;
    const float* wp = W1T + (size_t)(ks * 64) * DDIM + o;
#pragma unroll 8
    for (int dd = 0; dd < 64; ++dd)
      p = fmaf(v2[ks * 64 + dd], wp[(size_t)dd * DDIM], p);
    red[ks][0][o] = p;
  }
  __syncthreads();
  if (ks == 0)
    su[o] = fmaxf(b1[o] + red[0][0][o] + red[1][0][o] + red[2][0][o] + red[3][0][o], 0.f);
  __syncthreads();
  // phase 4: W2 + residual
  {
    float p = 0.f;
    const float* wp = W2T + (size_t)(ks * 64) * DDIM + o;
#pragma unroll 8
    for (int dd = 0; dd < 64; ++dd)
      p = fmaf(su[ks * 64 + dd], wp[(size_t)dd * DDIM], p);
    red[ks][0][o] = p;
  }
  __syncthreads();
  if (ks == 0) {
    float out = v1[o] + b2[o] + red[0][0][o] + red[1][0][o] + red[2][0][o] + red[3][0][o];
    slots_out[(size_t)r * DDIM + o] = out;
    v2[o] = out;
  }
  __syncthreads();
  if (!compute_qk) return;
  // qk tail: LN(out)
  if (ks == 0) {
    float x = v2[o];
    float s2 = x, ss2 = x * x;
    wave_reduce2(s2, ss2);
    if (lane == 0) { scal[wid] = s2; scal[4 + wid] = ss2; }
  }
  __syncthreads();
  if (ks == 0) {
    float sS = scal[0] + scal[1] + scal[2] + scal[3];
    float sQ = scal[4] + scal[5] + scal[6] + scal[7];
    float m = sS * (1.f / DDIM);
    float rs = rsqrtf(sQ * (1.f / DDIM) - m * m + LN_EPS_C);
    su[o] = (v2[o] - m) * rs * g_sl[o] + be_sl[o];  // ln
  }
  __syncthreads();
  // q = bq + ln @ WqT
  {
    float p = 0.f;
    const float* wp = WqT + (size_t)(ks * 64) * DDIM + o;
#pragma unroll 8
    for (int dd = 0; dd < 64; ++dd)
      p = fmaf(su[ks * 64 + dd], wp[(size_t)dd * DDIM], p);
    red[ks][0][o] = p;
  }
  __syncthreads();
  if (ks == 0)
    sh[o] = bq[o] + red[0][0][o] + red[1][0][o] + red[2][0][o] + red[3][0][o];  // q
  __syncthreads();
  // qk = SCALE * (Wk^T q)
  {
    float p = 0.f;
    const float* wp = Wk + (size_t)(ks * 64) * DDIM + o;
#pragma unroll 8
    for (int dd = 0; dd < 64; ++dd)
      p = fmaf(sh[ks * 64 + dd], wp[(size_t)dd * DDIM], p);
    red[ks][0][o] = p;
  }
  __syncthreads();
  if (ks == 0) {
    float qkv = SCALE * (red[0][0][o] + red[1][0][o] + red[2][0][o] + red[3][0][o]);
    qk[(size_t)r * DDIM + o] = qkv;
    float v0 = sh[o] * bk[o], vG = g_in[o] * qkv, vB = be_in[o] * qkv;
    wave_reduce3(v0, vG, vB);
    if (lane == 0) { scal[wid] = v0; scal[4 + wid] = vG; scal[8 + wid] = vB; }
  }
  __syncthreads();
  if (t == 0) {
    float qkb = SCALE * (scal[0] + scal[1] + scal[2] + scal[3]);
    G[r] = scal[4] + scal[5] + scal[6] + scal[7];
    C0[r] = qkb + scal[8] + scal[9] + scal[10] + scal[11];
  }
}

extern "C" void kernel_launch(void* const* d_in, const int* in_sizes, int n_in,
                              void* d_out, int out_size, void* d_ws,
                              size_t ws_size, hipStream_t stream) {
  const float* inputs   = (const float*)d_in[0];
  const float* noise    = (const float*)d_in[1];
  const float* slots_mu = (const float*)d_in[2];
  const float* slots_ls = (const float*)d_in[3];
  const float* Wq   = (const float*)d_in[4];
  const float* bq   = (const float*)d_in[5];
  const float* Wk   = (const float*)d_in[6];
  const float* bk   = (const float*)d_in[7];
  const float* Wv   = (const float*)d_in[8];
  const float* bv   = (const float*)d_in[9];
  const float* W_ih = (const float*)d_in[10];
  const float* W_hh = (const float*)d_in[11];
  const float* b_ih = (const float*)d_in[12];
  const float* b_hh = (const float*)d_in[13];
  const float* W1   = (const float*)d_in[14];
  const float* b1   = (const float*)d_in[15];
  const float* W2   = (const float*)d_in[16];
  const float* b2   = (const float*)d_in[17];
  const float* g_in = (const float*)d_in[18];
  const float* be_in= (const float*)d_in[19];
  const float* g_sl = (const float*)d_in[20];
  const float* be_sl= (const float*)d_in[21];
  const float* g_ff = (const float*)d_in[22];
  const float* be_ff= (const float*)d_in[23];

  float* out_slots = (float*)d_out;                 // [32,8,256]
  float* out_attn  = (float*)d_out + SROWS * DDIM;  // [32,8,4096]

  float* w = (float*)d_ws;
  float* slots = w;  w += SROWS * DDIM;
  float* qk = w;     w += SROWS * DDIM;
  float* C0 = w;     w += SROWS;
  float* G = w;      w += SROWS;
  float* WqT = w;    w += DDIM * DDIM;
  float* WvT = w;    w += DDIM * DDIM;
  float* WihT = w;   w += DDIM * 3 * DDIM;
  float* WhhT = w;   w += DDIM * 3 * DDIM;
  float* W1T = w;    w += DDIM * DDIM;
  float* W2T = w;    w += DDIM * DDIM;
  float* S_part = w; w += NBATCH * NCHK * NSLOT;  // 16384
  __half* u_part = (__half*)w;  // [32][64][8][256] fp16 = 8 MB
  // total ws ~ 11.1 MB

  transpose_all_k<<<dim3(80, 8), 256, 0, stream>>>(
      Wq, Wv, W_ih, W_hh, W1, W2, WqT, WvT, WihT, WhhT, W1T, W2T);
  init_q_qk_k<<<SROWS, 256, 0, stream>>>(noise, slots_mu, slots_ls, slots,
                                         g_sl, be_sl, WqT, bq, Wk, bk, g_in,
                                         be_in, qk, C0, G);
  for (int it = 0; it < 3; ++it) {
    fused_attn_k<<<dim3(NBATCH, NCHK), 256, 0, stream>>>(
        inputs, g_in, be_in, qk, C0, G, out_attn, S_part, u_part,
        (it == 2) ? 1 : 0);
    float* sout = (it == 2) ? out_slots : slots;
    slot_update_k<<<SROWS, 1024, 0, stream>>>(
        u_part, S_part, slots, WvT, bv, WihT, WhhT, b_ih, b_hh, g_ff, be_ff,
        W1T, b1, W2T, b2, g_sl, be_sl, WqT, bq, Wk, bk, g_in, be_in, sout, qk,
        C0, G, (it == 2) ? 0 : 1);
  }
}

// Round 7
// 236.751 us; speedup vs baseline: 2.1026x; 1.2004x over previous
//
#include <hip/hip_runtime.h>
#include <hip/hip_fp16.h>
#include <cstdint>
#include <cstddef>

// SlotAttention, round 6 (round 5 + fixed 34-arg call site).
//  - iter 0: fused f32 pass reads X, computes LN inline (dots = rs*(P1-m*G)+C0),
//    writes x_ln as fp16 (xh) + u partials fp16 + S partials.
//  - iters 1,2: fused f16 pass reads xh only; dots = xh.qk + qkb. No LN math.
//  - slot_update: 1024-thread k-split chain with fp16 weights (halved L2 BW);
//    init mode seeds slots from noise and runs only the qk tail.

#define NTOK 4096
#define DDIM 256
#define NSLOT 8
#define NBATCH 32
#define NCHK 64                 // 64-token chunks
#define SROWS (NBATCH * NSLOT)  // 256 slot rows
#define SCALE 0.0625f
#define LN_EPS_C 1e-5f
#define ATTN_EPS_C 1e-8f

__device__ __forceinline__ void wave_reduce2(float& s, float& ss) {
#pragma unroll
  for (int off = 32; off > 0; off >>= 1) {
    s  += __shfl_down(s, off, 64);
    ss += __shfl_down(ss, off, 64);
  }
}
__device__ __forceinline__ void wave_reduce3(float& a, float& b, float& c) {
#pragma unroll
  for (int off = 32; off > 0; off >>= 1) {
    a += __shfl_down(a, off, 64);
    b += __shfl_down(b, off, 64);
    c += __shfl_down(c, off, 64);
  }
}

// transpose 6 weight matrices to fp16; plain-convert Wk to fp16.
// bz: Wq[0,8) Wv[8,16) Wih[16,40) Whh[40,64) W1[64,72) W2[72,80) Wk[80,88)
__global__ __launch_bounds__(256) void convert_weights_k(
    const float* __restrict__ Wq, const float* __restrict__ Wv,
    const float* __restrict__ Wih, const float* __restrict__ Whh,
    const float* __restrict__ W1, const float* __restrict__ W2,
    const float* __restrict__ Wk, __half* __restrict__ WqT,
    __half* __restrict__ WvT, __half* __restrict__ WihT,
    __half* __restrict__ WhhT, __half* __restrict__ W1T,
    __half* __restrict__ W2T, __half* __restrict__ Wk_h) {
  __shared__ float tile[32][33];
  int bz = blockIdx.x;
  int tx = threadIdx.x & 31, ty = threadIdx.x >> 5;
  if (bz >= 80) {  // plain convert Wk
    int ro = (bz - 80) * 32, cd = blockIdx.y * 32;
#pragma unroll
    for (int p = 0; p < 32; p += 8)
      Wk_h[(size_t)(ro + ty + p) * DDIM + cd + tx] =
          __float2half(Wk[(size_t)(ro + ty + p) * DDIM + cd + tx]);
    return;
  }
  const float* in; __half* out; int O, bo;
  if (bz < 8)       { in = Wq;  out = WqT;  O = 256; bo = bz; }
  else if (bz < 16) { in = Wv;  out = WvT;  O = 256; bo = bz - 8; }
  else if (bz < 40) { in = Wih; out = WihT; O = 768; bo = bz - 16; }
  else if (bz < 64) { in = Whh; out = WhhT; O = 768; bo = bz - 40; }
  else if (bz < 72) { in = W1;  out = W1T;  O = 256; bo = bz - 64; }
  else              { in = W2;  out = W2T;  O = 256; bo = bz - 72; }
  int ro = bo * 32, cd = blockIdx.y * 32;
#pragma unroll
  for (int p = 0; p < 32; p += 8)
    tile[ty + p][tx] = in[(size_t)(ro + ty + p) * DDIM + cd + tx];
  __syncthreads();
#pragma unroll
  for (int p = 0; p < 32; p += 8)
    out[(size_t)(cd + ty + p) * O + ro + tx] = __float2half(tile[tx][ty + p]);
}

// iter 0 token pass (round-4 proven structure + xh store). 256 threads,
// block = (b, 64-token chunk c), two 32-token halves.
__global__ __launch_bounds__(256) void fused_attn_f32_k(
    const float* __restrict__ X, const float* __restrict__ g,
    const float* __restrict__ be, const float* __restrict__ qk,
    const float* __restrict__ C0, const float* __restrict__ Gv,
    float* __restrict__ S_part, __half* __restrict__ u_part,
    __half* __restrict__ xh_out) {
  __shared__ float sx[32][260];
  __shared__ float sqkg[NSLOT][DDIM];
  __shared__ float part[8][10][32];
  __shared__ float sm[32], srd[32];
  __shared__ float sC0[NSLOT], sG[NSLOT], sS[NSLOT];
  int b = blockIdx.x, c = blockIdx.y, t = threadIdx.x;
  int tj = t & 31, qd = t >> 5;
#pragma unroll
  for (int i = 0; i < NSLOT; ++i)
    sqkg[i][t] = qk[((size_t)b * NSLOT + i) * DDIM + t] * g[t];
  if (t < NSLOT) { sC0[t] = C0[b * NSLOT + t]; sG[t] = Gv[b * NSLOT + t]; sS[t] = 0.f; }
  float gt = g[t], bet = be[t];
  float acc[NSLOT] = {};
  const size_t base = (size_t)b * NTOK + (size_t)c * 64;
#pragma unroll
  for (int half = 0; half < 2; ++half) {
    __syncthreads();
#pragma unroll
    for (int it = 0; it < 8; ++it) {
      int e = it * 256 + t;
      int row = e >> 6, c4 = e & 63;
      float4 v = *(const float4*)(X + (base + half * 32 + row) * DDIM + c4 * 4);
      *(float4*)&sx[row][c4 * 4] = v;
    }
    __syncthreads();
    float s = 0.f, ss = 0.f, p[NSLOT] = {};
#pragma unroll
    for (int d4 = 0; d4 < 8; ++d4) {
      float4 xv = *(const float4*)&sx[tj][qd * 32 + d4 * 4];
      s += xv.x + xv.y + xv.z + xv.w;
      ss += xv.x * xv.x + xv.y * xv.y + xv.z * xv.z + xv.w * xv.w;
#pragma unroll
      for (int i = 0; i < NSLOT; ++i) {
        float4 qv = *(const float4*)&sqkg[i][qd * 32 + d4 * 4];
        p[i] += xv.x * qv.x + xv.y * qv.y + xv.z * qv.z + xv.w * qv.w;
      }
    }
#pragma unroll
    for (int i = 0; i < NSLOT; ++i) part[qd][i][tj] = p[i];
    part[qd][8][tj] = s;
    part[qd][9][tj] = ss;
    __syncthreads();
    if (t < 32) {
      float s1 = 0.f, s2 = 0.f;
#pragma unroll
      for (int q2 = 0; q2 < 8; ++q2) { s1 += part[q2][8][t]; s2 += part[q2][9][t]; }
      float m = s1 * (1.f / DDIM);
      float rs = rsqrtf(s2 * (1.f / DDIM) - m * m + LN_EPS_C);
      sm[t] = m;
      srd[t] = rs;
      float dots[NSLOT], mx = -1e30f;
#pragma unroll
      for (int i = 0; i < NSLOT; ++i) {
        float P1 = 0.f;
#pragma unroll
        for (int q2 = 0; q2 < 8; ++q2) P1 += part[q2][i][t];
        dots[i] = rs * (P1 - m * sG[i]) + sC0[i];
        mx = fmaxf(mx, dots[i]);
      }
      float sum = 0.f;
#pragma unroll
      for (int i = 0; i < NSLOT; ++i) { dots[i] = expf(dots[i] - mx); sum += dots[i]; }
      float inv = 1.f / sum;
#pragma unroll
      for (int i = 0; i < NSLOT; ++i) {
        float ae = dots[i] * inv + ATTN_EPS_C;
        part[i][8][t] = ae;
        float ps = ae;
#pragma unroll
        for (int off = 16; off > 0; off >>= 1) ps += __shfl_down(ps, off, 64);
        if (t == 0) sS[i] += ps;
      }
    }
    __syncthreads();
#pragma unroll 8
    for (int jj = 0; jj < 32; ++jj) {
      float x = sx[jj][t];
      float xl = (x - sm[jj]) * srd[jj] * gt + bet;
      xh_out[(base + half * 32 + jj) * DDIM + t] = __float2half(xl);
#pragma unroll
      for (int i = 0; i < NSLOT; ++i) acc[i] = fmaf(xl, part[i][8][jj], acc[i]);
    }
  }
  __half* upb = u_part + (((size_t)b * NCHK + c) * NSLOT) * DDIM + t;
#pragma unroll
  for (int i = 0; i < NSLOT; ++i) upb[(size_t)i * DDIM] = __float2half(acc[i]);
  if (t < NSLOT) S_part[((size_t)b * NCHK + c) * NSLOT + t] = sS[t];
}

// iters 1,2 token pass: reads fp16 xh; dots = xh.qk + qkb. 256 threads.
__global__ __launch_bounds__(256) void fused_attn_f16_k(
    const __half* __restrict__ xh, const float* __restrict__ qk,
    const float* __restrict__ qkb, float* __restrict__ attn_out,
    float* __restrict__ S_part, __half* __restrict__ u_part, int write_attn) {
  __shared__ __half sx[64][258];          // 516B rows: stride 129 dwords = 1 mod 32
  __shared__ float2 sqkf[NSLOT][128];
  __shared__ float part[4][NSLOT][64];
  __shared__ float sa[NSLOT][64];
  __shared__ float sC0[NSLOT], sS[NSLOT];
  int b = blockIdx.x, c = blockIdx.y, t = threadIdx.x;
  {
    int i = t >> 5, p2 = t & 31;
    const float* qr = qk + ((size_t)b * NSLOT + i) * DDIM;
#pragma unroll
    for (int kk = 0; kk < 4; ++kk) {
      int col = p2 * 4 + kk;
      sqkf[i][col] = make_float2(qr[col * 2], qr[col * 2 + 1]);
    }
  }
  if (t < NSLOT) sC0[t] = qkb[b * NSLOT + t];
  const size_t base = (size_t)b * NTOK + (size_t)c * 64;
#pragma unroll
  for (int it = 0; it < 8; ++it) {
    int e = it * 256 + t;
    int row = e >> 5, c8 = e & 31;
    const __half* src = xh + (base + row) * DDIM + c8 * 8;
    uint4 v = *(const uint4*)src;
    __half2* dst = (__half2*)&sx[row][c8 * 8];
    dst[0] = ((const __half2*)&v)[0];
    dst[1] = ((const __half2*)&v)[1];
    dst[2] = ((const __half2*)&v)[2];
    dst[3] = ((const __half2*)&v)[3];
  }
  __syncthreads();
  // phase A: tj = token, qd = 64-dim slice
  int tj = t & 63, qd = t >> 6;
  float p[NSLOT] = {};
  const __half2* xrow = (const __half2*)&sx[tj][qd * 64];
#pragma unroll
  for (int dd2 = 0; dd2 < 32; ++dd2) {
    float2 xf = __half22float2(xrow[dd2]);
#pragma unroll
    for (int i = 0; i < NSLOT; ++i) {
      float2 qf = sqkf[i][qd * 32 + dd2];
      p[i] = fmaf(xf.x, qf.x, fmaf(xf.y, qf.y, p[i]));
    }
  }
#pragma unroll
  for (int i = 0; i < NSLOT; ++i) part[qd][i][tj] = p[i];
  __syncthreads();
  // phase B: wave 0 (t<64) per-token softmax over 8 slots
  if (t < 64) {
    float dots[NSLOT], mx = -1e30f;
#pragma unroll
    for (int i = 0; i < NSLOT; ++i) {
      dots[i] = part[0][i][t] + part[1][i][t] + part[2][i][t] + part[3][i][t] +
                sC0[i];
      mx = fmaxf(mx, dots[i]);
    }
    float sum = 0.f;
#pragma unroll
    for (int i = 0; i < NSLOT; ++i) { dots[i] = expf(dots[i] - mx); sum += dots[i]; }
    float inv = 1.f / sum;
#pragma unroll
    for (int i = 0; i < NSLOT; ++i) {
      float a = dots[i] * inv;
      if (write_attn)
        attn_out[((size_t)b * NSLOT + i) * NTOK + c * 64 + t] = a;
      float ae = a + ATTN_EPS_C;
      sa[i][t] = ae;
      float ps = ae;
#pragma unroll
      for (int off = 32; off > 0; off >>= 1) ps += __shfl_down(ps, off, 64);
      if (t == 0) sS[i] = ps;
    }
  }
  __syncthreads();
  // phase C: thread = dim
  float acc[NSLOT] = {};
#pragma unroll 8
  for (int jj = 0; jj < 64; ++jj) {
    float x = __half2float(sx[jj][t]);
#pragma unroll
    for (int i = 0; i < NSLOT; ++i) acc[i] = fmaf(x, sa[i][jj], acc[i]);
  }
  __half* upb = u_part + (((size_t)b * NCHK + c) * NSLOT) * DDIM + t;
#pragma unroll
  for (int i = 0; i < NSLOT; ++i) upb[(size_t)i * DDIM] = __float2half(acc[i]);
  if (t < NSLOT) S_part[((size_t)b * NCHK + c) * NSLOT + t] = sS[t];
}

// slot path, 1024 threads: o = t&255, ks = t>>8. fp16 weights.
// init mode: slots = mu+exp(logsig)*noise, then qk tail only.
__global__ __launch_bounds__(1024) void slot_update_k(
    const __half* __restrict__ u_part, const float* __restrict__ S_part,
    const float* __restrict__ slots_in, const __half* __restrict__ WvT,
    const float* __restrict__ bv, const __half* __restrict__ WihT,
    const __half* __restrict__ WhhT, const float* __restrict__ b_ih,
    const float* __restrict__ b_hh, const float* __restrict__ g_ff,
    const float* __restrict__ be_ff, const __half* __restrict__ W1T,
    const float* __restrict__ b1, const __half* __restrict__ W2T,
    const float* __restrict__ b2, const float* __restrict__ g_sl,
    const float* __restrict__ be_sl, const __half* __restrict__ WqT,
    const float* __restrict__ bq, const __half* __restrict__ Wk_h,
    const float* __restrict__ bk, const float* __restrict__ g_in,
    const float* __restrict__ be_in, const float* __restrict__ noise,
    const float* __restrict__ mu, const float* __restrict__ logsig,
    float* __restrict__ slots_out, float* __restrict__ qk,
    float* __restrict__ C0, float* __restrict__ qkb_out,
    float* __restrict__ G, int init, int compute_qk) {
  __shared__ float red[4][6][DDIM];
  __shared__ float su[DDIM], sh[DDIM], supd[DDIM], v1[DDIM], v2[DDIM];
  __shared__ float scal[16];
  int r = blockIdx.x, t = threadIdx.x;
  int b = r >> 3, i = r & 7;
  int o = t & 255, ks = t >> 8;
  int lane = t & 63, wid = t >> 6;
  if (init) {
    if (ks == 0) {
      float ns = mu[o] + expf(logsig[o]) * noise[(size_t)r * DDIM + o];
      slots_out[(size_t)r * DDIM + o] = ns;
      v2[o] = ns;
    }
    __syncthreads();
  } else {
    // phase 0: u partials + S reduce + h load
    {
      float up = 0.f;
      const __half* upp =
          u_part + (((size_t)b * NCHK + ks * 16) * NSLOT + i) * DDIM + o;
#pragma unroll
      for (int cc = 0; cc < 16; ++cc)
        up += __half2float(upp[(size_t)cc * (NSLOT * DDIM)]);
      red[ks][0][o] = up;
    }
    if (t < 64) {
      float sp = S_part[((size_t)b * NCHK + t) * NSLOT + i];
#pragma unroll
      for (int off = 32; off > 0; off >>= 1) sp += __shfl_down(sp, off, 64);
      if (t == 0) scal[0] = sp;
    }
    if (ks == 0) sh[o] = slots_in[(size_t)r * DDIM + o];
    __syncthreads();
    if (ks == 0) {
      float invS = 1.f / scal[0];
      su[o] = (red[0][0][o] + red[1][0][o] + red[2][0][o] + red[3][0][o]) * invS;
    }
    __syncthreads();
    // phase 1: Wv
    {
      float p = 0.f;
      const __half* wp = WvT + (size_t)(ks * 64) * DDIM + o;
#pragma unroll 8
      for (int dd = 0; dd < 64; ++dd)
        p = fmaf(su[ks * 64 + dd], __half2float(wp[(size_t)dd * DDIM]), p);
      red[ks][0][o] = p;
    }
    __syncthreads();
    if (ks == 0)
      supd[o] = bv[o] + red[0][0][o] + red[1][0][o] + red[2][0][o] + red[3][0][o];
    __syncthreads();
    // phase 2: GRU (6 matvecs)
    {
      float p0 = 0, p1 = 0, p2 = 0, p3 = 0, p4 = 0, p5 = 0;
      const __half* pi = WihT + (size_t)(ks * 64) * (3 * DDIM) + o;
      const __half* ph = WhhT + (size_t)(ks * 64) * (3 * DDIM) + o;
#pragma unroll 4
      for (int dd = 0; dd < 64; ++dd) {
        float ud = supd[ks * 64 + dd], hd = sh[ks * 64 + dd];
        size_t off = (size_t)dd * (3 * DDIM);
        p0 = fmaf(ud, __half2float(pi[off]), p0);
        p1 = fmaf(ud, __half2float(pi[off + DDIM]), p1);
        p2 = fmaf(ud, __half2float(pi[off + 2 * DDIM]), p2);
        p3 = fmaf(hd, __half2float(ph[off]), p3);
        p4 = fmaf(hd, __half2float(ph[off + DDIM]), p4);
        p5 = fmaf(hd, __half2float(ph[off + 2 * DDIM]), p5);
      }
      red[ks][0][o] = p0; red[ks][1][o] = p1; red[ks][2][o] = p2;
      red[ks][3][o] = p3; red[ks][4][o] = p4; red[ks][5][o] = p5;
    }
    __syncthreads();
    if (ks == 0) {
      float air = b_ih[o] + red[0][0][o] + red[1][0][o] + red[2][0][o] + red[3][0][o];
      float aiz = b_ih[DDIM + o] + red[0][1][o] + red[1][1][o] + red[2][1][o] + red[3][1][o];
      float ain = b_ih[2 * DDIM + o] + red[0][2][o] + red[1][2][o] + red[2][2][o] + red[3][2][o];
      float ahr = b_hh[o] + red[0][3][o] + red[1][3][o] + red[2][3][o] + red[3][3][o];
      float ahz = b_hh[DDIM + o] + red[0][4][o] + red[1][4][o] + red[2][4][o] + red[3][4][o];
      float ahn = b_hh[2 * DDIM + o] + red[0][5][o] + red[1][5][o] + red[2][5][o] + red[3][5][o];
      float rg = 1.f / (1.f + expf(-(air + ahr)));
      float zg = 1.f / (1.f + expf(-(aiz + ahz)));
      float ng = tanhf(ain + rg * ahn);
      float nh = (1.f - zg) * ng + zg * sh[o];
      v1[o] = nh;
      float s2 = nh, ss2 = nh * nh;
      wave_reduce2(s2, ss2);
      if (lane == 0) { scal[wid] = s2; scal[4 + wid] = ss2; }
    }
    __syncthreads();
    if (ks == 0) {
      float sS = scal[0] + scal[1] + scal[2] + scal[3];
      float sQ = scal[4] + scal[5] + scal[6] + scal[7];
      float m = sS * (1.f / DDIM);
      float rs = rsqrtf(sQ * (1.f / DDIM) - m * m + LN_EPS_C);
      v2[o] = (v1[o] - m) * rs * g_ff[o] + be_ff[o];
    }
    __syncthreads();
    // phase 3: W1 + relu
    {
      float p = 0.f;
      const __half* wp = W1T + (size_t)(ks * 64) * DDIM + o;
#pragma unroll 8
      for (int dd = 0; dd < 64; ++dd)
        p = fmaf(v2[ks * 64 + dd], __half2float(wp[(size_t)dd * DDIM]), p);
      red[ks][0][o] = p;
    }
    __syncthreads();
    if (ks == 0)
      su[o] = fmaxf(b1[o] + red[0][0][o] + red[1][0][o] + red[2][0][o] + red[3][0][o], 0.f);
    __syncthreads();
    // phase 4: W2 + residual
    {
      float p = 0.f;
      const __half* wp = W2T + (size_t)(ks * 64) * DDIM + o;
#pragma unroll 8
      for (int dd = 0; dd < 64; ++dd)
        p = fmaf(su[ks * 64 + dd], __half2float(wp[(size_t)dd * DDIM]), p);
      red[ks][0][o] = p;
    }
    __syncthreads();
    if (ks == 0) {
      float out = v1[o] + b2[o] + red[0][0][o] + red[1][0][o] + red[2][0][o] + red[3][0][o];
      slots_out[(size_t)r * DDIM + o] = out;
      v2[o] = out;
    }
    __syncthreads();
  }
  if (!compute_qk) return;
  // qk tail: LN(v2) -> q -> qk, constants
  if (ks == 0) {
    float x = v2[o];
    float s2 = x, ss2 = x * x;
    wave_reduce2(s2, ss2);
    if (lane == 0) { scal[wid] = s2; scal[4 + wid] = ss2; }
  }
  __syncthreads();
  if (ks == 0) {
    float sS = scal[0] + scal[1] + scal[2] + scal[3];
    float sQ = scal[4] + scal[5] + scal[6] + scal[7];
    float m = sS * (1.f / DDIM);
    float rs = rsqrtf(sQ * (1.f / DDIM) - m * m + LN_EPS_C);
    su[o] = (v2[o] - m) * rs * g_sl[o] + be_sl[o];
  }
  __syncthreads();
  {
    float p = 0.f;
    const __half* wp = WqT + (size_t)(ks * 64) * DDIM + o;
#pragma unroll 8
    for (int dd = 0; dd < 64; ++dd)
      p = fmaf(su[ks * 64 + dd], __half2float(wp[(size_t)dd * DDIM]), p);
    red[ks][0][o] = p;
  }
  __syncthreads();
  if (ks == 0)
    sh[o] = bq[o] + red[0][0][o] + red[1][0][o] + red[2][0][o] + red[3][0][o];
  __syncthreads();
  {
    float p = 0.f;
    const __half* wp = Wk_h + (size_t)(ks * 64) * DDIM + o;
#pragma unroll 8
    for (int dd = 0; dd < 64; ++dd)
      p = fmaf(sh[ks * 64 + dd], __half2float(wp[(size_t)dd * DDIM]), p);
    red[ks][0][o] = p;
  }
  __syncthreads();
  if (ks == 0) {
    float qkv = SCALE * (red[0][0][o] + red[1][0][o] + red[2][0][o] + red[3][0][o]);
    qk[(size_t)r * DDIM + o] = qkv;
    float v0 = sh[o] * bk[o], vG = g_in[o] * qkv, vB = be_in[o] * qkv;
    wave_reduce3(v0, vG, vB);
    if (lane == 0) { scal[wid] = v0; scal[4 + wid] = vG; scal[8 + wid] = vB; }
  }
  __syncthreads();
  if (t == 0) {
    float qkb = SCALE * (scal[0] + scal[1] + scal[2] + scal[3]);
    qkb_out[r] = qkb;
    G[r] = scal[4] + scal[5] + scal[6] + scal[7];
    C0[r] = qkb + scal[8] + scal[9] + scal[10] + scal[11];
  }
}

extern "C" void kernel_launch(void* const* d_in, const int* in_sizes, int n_in,
                              void* d_out, int out_size, void* d_ws,
                              size_t ws_size, hipStream_t stream) {
  const float* inputs   = (const float*)d_in[0];
  const float* noise    = (const float*)d_in[1];
  const float* slots_mu = (const float*)d_in[2];
  const float* slots_ls = (const float*)d_in[3];
  const float* Wq   = (const float*)d_in[4];
  const float* bq   = (const float*)d_in[5];
  const float* Wk   = (const float*)d_in[6];
  const float* bk   = (const float*)d_in[7];
  const float* Wv   = (const float*)d_in[8];
  const float* bv   = (const float*)d_in[9];
  const float* W_ih = (const float*)d_in[10];
  const float* W_hh = (const float*)d_in[11];
  const float* b_ih = (const float*)d_in[12];
  const float* b_hh = (const float*)d_in[13];
  const float* W1   = (const float*)d_in[14];
  const float* b1   = (const float*)d_in[15];
  const float* W2   = (const float*)d_in[16];
  const float* b2   = (const float*)d_in[17];
  const float* g_in = (const float*)d_in[18];
  const float* be_in= (const float*)d_in[19];
  const float* g_sl = (const float*)d_in[20];
  const float* be_sl= (const float*)d_in[21];
  const float* g_ff = (const float*)d_in[22];
  const float* be_ff= (const float*)d_in[23];

  float* out_slots = (float*)d_out;                 // [32,8,256]
  float* out_attn  = (float*)d_out + SROWS * DDIM;  // [32,8,4096]

  float* w = (float*)d_ws;
  float* slots = w;  w += SROWS * DDIM;
  float* qk = w;     w += SROWS * DDIM;
  float* C0 = w;     w += SROWS;
  float* qkb = w;    w += SROWS;
  float* G = w;      w += SROWS;
  float* S_part = w; w += NBATCH * NCHK * NSLOT;
  __half* h = (__half*)w;
  __half* xh = h;     h += (size_t)NBATCH * NTOK * DDIM;           // 67 MB
  __half* u_part = h; h += (size_t)NBATCH * NCHK * NSLOT * DDIM;   // 8 MB
  __half* WqT_h = h;  h += DDIM * DDIM;
  __half* WvT_h = h;  h += DDIM * DDIM;
  __half* WihT_h = h; h += DDIM * 3 * DDIM;
  __half* WhhT_h = h; h += DDIM * 3 * DDIM;
  __half* W1T_h = h;  h += DDIM * DDIM;
  __half* W2T_h = h;  h += DDIM * DDIM;
  __half* Wk_h = h;   h += DDIM * DDIM;
  // total ws ~ 78 MB (ws_size ~512 MB per harness fill)

  convert_weights_k<<<dim3(88, 8), 256, 0, stream>>>(
      Wq, Wv, W_ih, W_hh, W1, W2, Wk, WqT_h, WvT_h, WihT_h, WhhT_h, W1T_h,
      W2T_h, Wk_h);
  // init: slots from noise + qk/G/C0/qkb
  slot_update_k<<<SROWS, 1024, 0, stream>>>(
      u_part, S_part, slots, WvT_h, bv, WihT_h, WhhT_h, b_ih, b_hh, g_ff,
      be_ff, W1T_h, b1, W2T_h, b2, g_sl, be_sl, WqT_h, bq, Wk_h, bk, g_in,
      be_in, noise, slots_mu, slots_ls, slots, qk, C0, qkb, G, 1, 1);
  // iter 0: f32 pass (writes xh)
  fused_attn_f32_k<<<dim3(NBATCH, NCHK), 256, 0, stream>>>(
      inputs, g_in, be_in, qk, C0, G, S_part, u_part, xh);
  slot_update_k<<<SROWS, 1024, 0, stream>>>(
      u_part, S_part, slots, WvT_h, bv, WihT_h, WhhT_h, b_ih, b_hh, g_ff,
      be_ff, W1T_h, b1, W2T_h, b2, g_sl, be_sl, WqT_h, bq, Wk_h, bk, g_in,
      be_in, noise, slots_mu, slots_ls, slots, qk, C0, qkb, G, 0, 1);
  // iter 1: f16 pass
  fused_attn_f16_k<<<dim3(NBATCH, NCHK), 256, 0, stream>>>(
      xh, qk, qkb, out_attn, S_part, u_part, 0);
  slot_update_k<<<SROWS, 1024, 0, stream>>>(
      u_part, S_part, slots, WvT_h, bv, WihT_h, WhhT_h, b_ih, b_hh, g_ff,
      be_ff, W1T_h, b1, W2T_h, b2, g_sl, be_sl, WqT_h, bq, Wk_h, bk, g_in,
      be_in, noise, slots_mu, slots_ls, slots, qk, C0, qkb, G, 0, 1);
  // iter 2: f16 pass (writes attn) + final slot update -> out_slots
  fused_attn_f16_k<<<dim3(NBATCH, NCHK), 256, 0, stream>>>(
      xh, qk, qkb, out_attn, S_part, u_part, 1);
  slot_update_k<<<SROWS, 1024, 0, stream>>>(
      u_part, S_part, slots, WvT_h, bv, WihT_h, WhhT_h, b_ih, b_hh, g_ff,
      be_ff, W1T_h, b1, W2T_h, b2, g_sl, be_sl, WqT_h, bq, Wk_h, bk, g_in,
      be_in, noise, slots_mu, slots_ls, out_slots, qk, C0, qkb, G, 0, 0);
}